// Round 11
// baseline (146.985 us; speedup 1.0000x reference)
//
#include <hip/hip_runtime.h>
#include <stdint.h>

#define B_ROWS 32768
#define N_INP 256
#define N_HID 1024
#define NF 256
#define N_IT 100

typedef __attribute__((ext_vector_type(8))) _Float16 f16x8;
typedef __attribute__((ext_vector_type(4))) float f32x4;
typedef __attribute__((ext_vector_type(2))) _Float16 f16x2;
typedef uint32_t u32;

__device__ __forceinline__ ushort f2h(float f) {
  _Float16 h = (_Float16)f;               // v_cvt_f16_f32, RNE
  return *reinterpret_cast<ushort*>(&h);
}

__device__ __forceinline__ void async_copy16(const void* g, void* l) {
  __builtin_amdgcn_global_load_lds(
      (const __attribute__((address_space(1))) void*)g,
      (__attribute__((address_space(3))) void*)l, 16, 0, 0);
}

__device__ __forceinline__ f16x2 as_h2(u32 x) { return __builtin_bit_cast(f16x2, x); }
__device__ __forceinline__ u32 as_u32(f16x2 x) { return __builtin_bit_cast(u32, x); }
// packed f16 min (VOP3P, full rate); single 32-bit regs -> clean regalloc
__device__ __forceinline__ f16x2 min2(f16x2 a, f16x2 b) {
  f16x2 r;
  asm("v_pk_min_f16 %0, %1, %2" : "=v"(r) : "v"(a), "v"(b));
  return r;
}

// ---- prepass (fused): pack x -> f16 [B,256] + idx; convert W1/W2 -> f16 ----
__global__ void prep_kernel(const float* __restrict__ x,
                            const float* __restrict__ W1,
                            const float* __restrict__ W2,
                            ushort* __restrict__ xh,
                            ushort* __restrict__ w1h,
                            ushort* __restrict__ w2h,
                            int* __restrict__ idx) {
  if (blockIdx.x < 8192) {
    int t = blockIdx.x * 256 + threadIdx.x;          // B*64 threads
    int b = t >> 6, q = t & 63;
    const float* xr = x + (size_t)b * (N_INP + 1);
    float v0 = xr[q * 4 + 0], v1 = xr[q * 4 + 1], v2 = xr[q * 4 + 2], v3 = xr[q * 4 + 3];
    ushort4 u = make_ushort4(f2h(v0), f2h(v1), f2h(v2), f2h(v3));
    *reinterpret_cast<ushort4*>(xh + (size_t)b * 256 + q * 4) = u;
    if (q == 0) idx[b] = (int)rintf(xr[N_INP] * 255.0f);
  } else {
    int t = (blockIdx.x - 8192) * 256 + threadIdx.x; // 65536 threads
    float4 a = reinterpret_cast<const float4*>(W1)[t];
    float4 b = reinterpret_cast<const float4*>(W2)[t];
    reinterpret_cast<ushort4*>(w1h)[t] = make_ushort4(f2h(a.x), f2h(a.y), f2h(a.z), f2h(a.w));
    reinterpret_cast<ushort4*>(w2h)[t] = make_ushort4(f2h(b.x), f2h(b.y), f2h(b.z), f2h(b.w));
  }
}

// ---- C[M,N] = epi(A[M,K] @ Bw[N,K]^T + bias), f16 output ----
template <int RELU>
__global__ __launch_bounds__(256, 2) void gemm_bt(
    const ushort* __restrict__ A, const ushort* __restrict__ Bw,
    const float* __restrict__ bias, ushort* __restrict__ C,
    int M, int N, int K, int ntN) {
  __shared__ ushort As[2][128 * 64];
  __shared__ ushort Bs[2][128 * 64];
  const int tid = threadIdx.x;
  const int w = tid >> 6, l = tid & 63;
  // bijective XCD swizzle (grid%8==0 in all our launches)
  int bid = blockIdx.x;
  if (((int)gridDim.x & 7) == 0) {
    int cpx = (int)gridDim.x >> 3;
    bid = (bid & 7) * cpx + (bid >> 3);
  }
  const int tm = bid / ntN, tn = bid % ntN;
  const int wm = w >> 1, wn = w & 1;
  const char* Ab = (const char*)(A + (size_t)tm * 128 * K);
  const char* Bb = (const char*)(Bw + (size_t)tn * 128 * K);
  const int sA = K * 2;
  const int lrow = l >> 3;
  const int lcol = (l & 7) * 16;

  f32x4 acc[4][4];
#pragma unroll
  for (int i = 0; i < 4; ++i)
#pragma unroll
    for (int j = 0; j < 4; ++j) acc[i][j] = {0.f, 0.f, 0.f, 0.f};

  const int nkt = K / 64;
  {
    const char* ga = Ab + lrow * sA + lcol;
    const char* gb = Bb + lrow * sA + lcol;
#pragma unroll
    for (int i = 0; i < 4; ++i) {
      int c = w * 4 + i;
      async_copy16(ga + c * 8 * sA, (char*)&As[0][0] + c * 1024);
      async_copy16(gb + c * 8 * sA, (char*)&Bs[0][0] + c * 1024);
    }
  }
  __syncthreads();

  const int arow = wm * 64 + (l & 15);
  const int brow = wn * 64 + (l & 15);
  const int koff = (l >> 4) * 8;

  for (int kt = 0; kt < nkt; ++kt) {
    const int buf = kt & 1;
    if (kt + 1 < nkt) {
      const char* ga = Ab + (kt + 1) * 128 + lrow * sA + lcol;
      const char* gb = Bb + (kt + 1) * 128 + lrow * sA + lcol;
#pragma unroll
      for (int i = 0; i < 4; ++i) {
        int c = w * 4 + i;
        async_copy16(ga + c * 8 * sA, (char*)&As[buf ^ 1][0] + c * 1024);
        async_copy16(gb + c * 8 * sA, (char*)&Bs[buf ^ 1][0] + c * 1024);
      }
    }
#pragma unroll
    for (int ks = 0; ks < 2; ++ks) {
      f16x8 af[4], bfr[4];
#pragma unroll
      for (int mi = 0; mi < 4; ++mi)
        af[mi] = *(const f16x8*)&As[buf][(arow + mi * 16) * 64 + ks * 32 + koff];
#pragma unroll
      for (int ni = 0; ni < 4; ++ni)
        bfr[ni] = *(const f16x8*)&Bs[buf][(brow + ni * 16) * 64 + ks * 32 + koff];
#pragma unroll
      for (int mi = 0; mi < 4; ++mi)
#pragma unroll
        for (int ni = 0; ni < 4; ++ni)
          acc[mi][ni] = __builtin_amdgcn_mfma_f32_16x16x32_f16(
              af[mi], bfr[ni], acc[mi][ni], 0, 0, 0);
    }
    __syncthreads();
  }

  const int grow0 = tm * 128 + wm * 64 + (l >> 4) * 4;
  const int gcol0 = tn * 128 + wn * 64 + (l & 15);
#pragma unroll
  for (int ni = 0; ni < 4; ++ni) {
    const int col = gcol0 + ni * 16;
    const float bv = bias[col];
#pragma unroll
    for (int mi = 0; mi < 4; ++mi) {
      const int row = grow0 + mi * 16;
#pragma unroll
      for (int r = 0; r < 4; ++r) {
        float v = acc[mi][ni][r] + bv;
        if (RELU) v = fmaxf(v, 0.f);
        C[(size_t)(row + r) * N + col] = f2h(v);
      }
    }
  }
}

// ---- convex fixed-point (100 iters) + gather, PACKED f16, 2-way ILP ----
// y_i <- min(y_i, 0.5*(y_{i-1}+y_{i+1})); result = y. 16 lanes/row, 16
// feats/lane (8 f16x2). ONE WAVE PER BLOCK (no LDS/barriers -> max resident
// waves per CU); each wave runs TWO independent 4-row groups (A: rows
// base..base+3, B: rows base+4..base+7) with interleaved iteration bodies ->
// 2 independent dependency chains hide VALU/DS latency within the wave.
__global__ void convex_gather(
    const ushort* __restrict__ xqh, const int* __restrict__ idx,
    float* __restrict__ out) {
  const int l = threadIdx.x;            // 64 threads = 1 wave
  const int q = l & 15;                 // lane within row
  const int base = blockIdx.x * 8;
  const int rowA = base + (l >> 4);
  const int rowB = rowA + 4;

  f16x2 hA[8], hB[8];
  {
    const uint4* sa = reinterpret_cast<const uint4*>(xqh + (size_t)rowA * 256 + q * 16);
    const uint4* sb = reinterpret_cast<const uint4*>(xqh + (size_t)rowB * 256 + q * 16);
    uint4 a0 = sa[0], a1 = sa[1], b0 = sb[0], b1 = sb[1];
    hA[0] = as_h2(a0.x); hA[1] = as_h2(a0.y); hA[2] = as_h2(a0.z); hA[3] = as_h2(a0.w);
    hA[4] = as_h2(a1.x); hA[5] = as_h2(a1.y); hA[6] = as_h2(a1.z); hA[7] = as_h2(a1.w);
    hB[0] = as_h2(b0.x); hB[1] = as_h2(b0.y); hB[2] = as_h2(b0.z); hB[3] = as_h2(b0.w);
    hB[4] = as_h2(b1.x); hB[5] = as_h2(b1.y); hB[6] = as_h2(b1.z); hB[7] = as_h2(b1.w);
  }
  const int iiA = idx[rowA];
  const int iiB = idx[rowB];
  const int upIdx = ((l - 1) & 63) * 4;
  const int dnIdx = ((l + 1) & 63) * 4;
  const bool fixP = (q == 0);
  const bool fixN = (q == 15);
  const f16x2 halfc = {(_Float16)0.5f, (_Float16)0.5f};

  // prologue halos
  u32 PA = __builtin_amdgcn_ds_bpermute(upIdx, as_u32(hA[7]));
  u32 NA = __builtin_amdgcn_ds_bpermute(dnIdx, as_u32(hA[0]));
  u32 PB = __builtin_amdgcn_ds_bpermute(upIdx, as_u32(hB[7]));
  u32 NB = __builtin_amdgcn_ds_bpermute(dnIdx, as_u32(hB[0]));

#pragma unroll 2
  for (int it = 0; it < N_IT; ++it) {
    u32 PfA = fixP ? 0x7C000000u : PA;   // prev.hi = +inf sentinel
    u32 NfA = fixN ? 0x00007C00u : NA;   // next.lo = +inf sentinel
    u32 PfB = fixP ? 0x7C000000u : PB;
    u32 NfB = fixN ? 0x00007C00u : NB;
    f16x2 sA[9], sB[9];                  // shifted streams from OLD state
    sA[0] = as_h2(__builtin_amdgcn_alignbit(as_u32(hA[0]), PfA, 16));
    sB[0] = as_h2(__builtin_amdgcn_alignbit(as_u32(hB[0]), PfB, 16));
#pragma unroll
    for (int t = 0; t < 7; ++t) {
      sA[t + 1] = as_h2(__builtin_amdgcn_alignbit(as_u32(hA[t + 1]), as_u32(hA[t]), 16));
      sB[t + 1] = as_h2(__builtin_amdgcn_alignbit(as_u32(hB[t + 1]), as_u32(hB[t]), 16));
    }
    sA[8] = as_h2(__builtin_amdgcn_alignbit(NfA, as_u32(hA[7]), 16));
    sB[8] = as_h2(__builtin_amdgcn_alignbit(NfB, as_u32(hB[7]), 16));
    // boundary regs first; issue next halos under the interior work
    hA[0] = min2(hA[0], (sA[0] + sA[1]) * halfc);
    hA[7] = min2(hA[7], (sA[7] + sA[8]) * halfc);
    hB[0] = min2(hB[0], (sB[0] + sB[1]) * halfc);
    hB[7] = min2(hB[7], (sB[7] + sB[8]) * halfc);
    PA = __builtin_amdgcn_ds_bpermute(upIdx, as_u32(hA[7]));
    NA = __builtin_amdgcn_ds_bpermute(dnIdx, as_u32(hA[0]));
    PB = __builtin_amdgcn_ds_bpermute(upIdx, as_u32(hB[7]));
    NB = __builtin_amdgcn_ds_bpermute(dnIdx, as_u32(hB[0]));
#pragma unroll
    for (int t = 1; t < 7; ++t) {
      hA[t] = min2(hA[t], (sA[t] + sA[t + 1]) * halfc);
      hB[t] = min2(hB[t], (sB[t] + sB[t + 1]) * halfc);
    }
  }

  // gather: cndmask tree over the 8 b32 regs per group, pick half, cvt, shfl
  u32 rA[8], rB[8];
#pragma unroll
  for (int t = 0; t < 8; ++t) { rA[t] = as_u32(hA[t]); rB[t] = as_u32(hB[t]); }
  const int srA = (iiA >> 1) & 7, srB = (iiB >> 1) & 7;
#pragma unroll
  for (int step = 4; step >= 1; step >>= 1) {
#pragma unroll
    for (int k = 0; k < 4; ++k) {
      if (k < step) {
        rA[k] = (srA & step) ? rA[k + step] : rA[k];
        rB[k] = (srB & step) ? rB[k + step] : rB[k];
      }
    }
  }
  ushort hvA = (iiA & 1) ? (ushort)(rA[0] >> 16) : (ushort)(rA[0] & 0xffffu);
  ushort hvB = (iiB & 1) ? (ushort)(rB[0] >> 16) : (ushort)(rB[0] & 0xffffu);
  float vA = (float)__builtin_bit_cast(_Float16, hvA);
  float vB = (float)__builtin_bit_cast(_Float16, hvB);
  vA = __shfl(vA, (l & ~15) | (iiA >> 4));
  vB = __shfl(vB, (l & ~15) | (iiB >> 4));
  if (q == 0) {
    out[rowA] = vA;
    out[rowB] = vB;
  }
}

extern "C" void kernel_launch(void* const* d_in, const int* in_sizes, int n_in,
                              void* d_out, int out_size, void* d_ws, size_t ws_size,
                              hipStream_t stream) {
  const float* x = (const float*)d_in[0];
  const float* W1 = (const float*)d_in[1];
  const float* b1 = (const float*)d_in[2];
  const float* W2 = (const float*)d_in[3];
  const float* b2 = (const float*)d_in[4];
  float* out = (float*)d_out;

  // workspace layout (16B-aligned)
  char* ws = (char*)d_ws;
  ushort* xh  = (ushort*)ws;                    // 16,777,216 B  x f16 [B,256]
  ushort* w1h = (ushort*)(ws + 16777216);       //    524,288 B
  ushort* w2h = (ushort*)(ws + 17301504);       //    524,288 B
  int*    idx = (int*)  (ws + 17825792);        //    131,072 B
  ushort* xqh = (ushort*)(ws + 17956864);       // 16,777,216 B  x_ f16 [B,256]
  ushort* h   = (ushort*)(ws + 34734080);       // chunk*2048 B  h f16 [chunk,1024]

  const size_t fixed = 34734080;
  int chunk = 2048;
  if (ws_size >= fixed + (size_t)32768 * 2048) chunk = 32768;
  else if (ws_size >= fixed + (size_t)16384 * 2048) chunk = 16384;
  else if (ws_size >= fixed + (size_t)8192 * 2048) chunk = 8192;
  else if (ws_size >= fixed + (size_t)4096 * 2048) chunk = 4096;

  prep_kernel<<<8448, 256, 0, stream>>>(x, W1, W2, xh, w1h, w2h, idx);

  for (int m0 = 0; m0 < B_ROWS; m0 += chunk) {
    int curM = (B_ROWS - m0 < chunk) ? (B_ROWS - m0) : chunk;
    dim3 g1((curM / 128) * (N_HID / 128));
    gemm_bt<1><<<g1, 256, 0, stream>>>(xh + (size_t)m0 * 256, w1h, b1, h,
                                       curM, N_HID, N_INP, N_HID / 128);
    dim3 g2((curM / 128) * (NF / 128));
    gemm_bt<0><<<g2, 256, 0, stream>>>(h, w2h, b2, xqh + (size_t)m0 * 256,
                                       curM, NF, N_HID, NF / 128);
  }
  convex_gather<<<B_ROWS / 8, 64, 0, stream>>>(xqh, idx, out);
}

// Round 12
// 144.973 us; speedup vs baseline: 1.0139x; 1.0139x over previous
//
#include <hip/hip_runtime.h>
#include <stdint.h>

#define B_ROWS 32768
#define N_INP 256
#define N_HID 1024
#define NF 256
#define N_IT 100

typedef __attribute__((ext_vector_type(8))) _Float16 f16x8;
typedef __attribute__((ext_vector_type(4))) float f32x4;
typedef __attribute__((ext_vector_type(2))) _Float16 f16x2;
typedef uint32_t u32;

__device__ __forceinline__ ushort f2h(float f) {
  _Float16 h = (_Float16)f;               // v_cvt_f16_f32, RNE
  return *reinterpret_cast<ushort*>(&h);
}

__device__ __forceinline__ void async_copy16(const void* g, void* l) {
  __builtin_amdgcn_global_load_lds(
      (const __attribute__((address_space(1))) void*)g,
      (__attribute__((address_space(3))) void*)l, 16, 0, 0);
}

__device__ __forceinline__ f16x2 as_h2(u32 x) { return __builtin_bit_cast(f16x2, x); }
__device__ __forceinline__ u32 as_u32(f16x2 x) { return __builtin_bit_cast(u32, x); }
// packed f16 min (VOP3P, full rate); single 32-bit regs -> clean regalloc
__device__ __forceinline__ f16x2 min2(f16x2 a, f16x2 b) {
  f16x2 r;
  asm("v_pk_min_f16 %0, %1, %2" : "=v"(r) : "v"(a), "v"(b));
  return r;
}

// ---- prepass (fused): pack x -> f16 [B,256] + idx; convert W1/W2 -> f16 ----
__global__ void prep_kernel(const float* __restrict__ x,
                            const float* __restrict__ W1,
                            const float* __restrict__ W2,
                            ushort* __restrict__ xh,
                            ushort* __restrict__ w1h,
                            ushort* __restrict__ w2h,
                            int* __restrict__ idx) {
  if (blockIdx.x < 8192) {
    int t = blockIdx.x * 256 + threadIdx.x;          // B*64 threads
    int b = t >> 6, q = t & 63;
    const float* xr = x + (size_t)b * (N_INP + 1);
    float v0 = xr[q * 4 + 0], v1 = xr[q * 4 + 1], v2 = xr[q * 4 + 2], v3 = xr[q * 4 + 3];
    ushort4 u = make_ushort4(f2h(v0), f2h(v1), f2h(v2), f2h(v3));
    *reinterpret_cast<ushort4*>(xh + (size_t)b * 256 + q * 4) = u;
    if (q == 0) idx[b] = (int)rintf(xr[N_INP] * 255.0f);
  } else {
    int t = (blockIdx.x - 8192) * 256 + threadIdx.x; // 65536 threads
    float4 a = reinterpret_cast<const float4*>(W1)[t];
    float4 b = reinterpret_cast<const float4*>(W2)[t];
    reinterpret_cast<ushort4*>(w1h)[t] = make_ushort4(f2h(a.x), f2h(a.y), f2h(a.z), f2h(a.w));
    reinterpret_cast<ushort4*>(w2h)[t] = make_ushort4(f2h(b.x), f2h(b.y), f2h(b.z), f2h(b.w));
  }
}

// ---- C[M,N] = epi(A[M,K] @ Bw[N,K]^T + bias), f16 output ----
template <int RELU>
__global__ __launch_bounds__(256, 2) void gemm_bt(
    const ushort* __restrict__ A, const ushort* __restrict__ Bw,
    const float* __restrict__ bias, ushort* __restrict__ C,
    int M, int N, int K, int ntN) {
  __shared__ ushort As[2][128 * 64];
  __shared__ ushort Bs[2][128 * 64];
  const int tid = threadIdx.x;
  const int w = tid >> 6, l = tid & 63;
  // bijective XCD swizzle (grid%8==0 in all our launches)
  int bid = blockIdx.x;
  if (((int)gridDim.x & 7) == 0) {
    int cpx = (int)gridDim.x >> 3;
    bid = (bid & 7) * cpx + (bid >> 3);
  }
  const int tm = bid / ntN, tn = bid % ntN;
  const int wm = w >> 1, wn = w & 1;
  const char* Ab = (const char*)(A + (size_t)tm * 128 * K);
  const char* Bb = (const char*)(Bw + (size_t)tn * 128 * K);
  const int sA = K * 2;
  const int lrow = l >> 3;
  const int lcol = (l & 7) * 16;

  f32x4 acc[4][4];
#pragma unroll
  for (int i = 0; i < 4; ++i)
#pragma unroll
    for (int j = 0; j < 4; ++j) acc[i][j] = {0.f, 0.f, 0.f, 0.f};

  const int nkt = K / 64;
  {
    const char* ga = Ab + lrow * sA + lcol;
    const char* gb = Bb + lrow * sA + lcol;
#pragma unroll
    for (int i = 0; i < 4; ++i) {
      int c = w * 4 + i;
      async_copy16(ga + c * 8 * sA, (char*)&As[0][0] + c * 1024);
      async_copy16(gb + c * 8 * sA, (char*)&Bs[0][0] + c * 1024);
    }
  }
  __syncthreads();

  const int arow = wm * 64 + (l & 15);
  const int brow = wn * 64 + (l & 15);
  const int koff = (l >> 4) * 8;

  for (int kt = 0; kt < nkt; ++kt) {
    const int buf = kt & 1;
    if (kt + 1 < nkt) {
      const char* ga = Ab + (kt + 1) * 128 + lrow * sA + lcol;
      const char* gb = Bb + (kt + 1) * 128 + lrow * sA + lcol;
#pragma unroll
      for (int i = 0; i < 4; ++i) {
        int c = w * 4 + i;
        async_copy16(ga + c * 8 * sA, (char*)&As[buf ^ 1][0] + c * 1024);
        async_copy16(gb + c * 8 * sA, (char*)&Bs[buf ^ 1][0] + c * 1024);
      }
    }
#pragma unroll
    for (int ks = 0; ks < 2; ++ks) {
      f16x8 af[4], bfr[4];
#pragma unroll
      for (int mi = 0; mi < 4; ++mi)
        af[mi] = *(const f16x8*)&As[buf][(arow + mi * 16) * 64 + ks * 32 + koff];
#pragma unroll
      for (int ni = 0; ni < 4; ++ni)
        bfr[ni] = *(const f16x8*)&Bs[buf][(brow + ni * 16) * 64 + ks * 32 + koff];
#pragma unroll
      for (int mi = 0; mi < 4; ++mi)
#pragma unroll
        for (int ni = 0; ni < 4; ++ni)
          acc[mi][ni] = __builtin_amdgcn_mfma_f32_16x16x32_f16(
              af[mi], bfr[ni], acc[mi][ni], 0, 0, 0);
    }
    __syncthreads();
  }

  const int grow0 = tm * 128 + wm * 64 + (l >> 4) * 4;
  const int gcol0 = tn * 128 + wn * 64 + (l & 15);
#pragma unroll
  for (int ni = 0; ni < 4; ++ni) {
    const int col = gcol0 + ni * 16;
    const float bv = bias[col];
#pragma unroll
    for (int mi = 0; mi < 4; ++mi) {
      const int row = grow0 + mi * 16;
#pragma unroll
      for (int r = 0; r < 4; ++r) {
        float v = acc[mi][ni][r] + bv;
        if (RELU) v = fmaxf(v, 0.f);
        C[(size_t)(row + r) * N + col] = f2h(v);
      }
    }
  }
}

// ---- convex fixed-point (100 iters) + gather, PACKED f16, IN-LANE runs ----
// y_i <- min(y_i, 0.5*(y_{i-1}+y_{i+1})); result = y.
// 4 lanes/row, 64 contiguous feats/lane as 32 f16x2 regs -> 16 rows/wave.
// Shifted stream via in-lane alignbit on adjacent regs; only 2 bpermutes
// per wave-iter (serve 16 rows). Update order: reg31 then reg0 (issue next
// halos), then interior regs 1..30 under the DS latency. Jacobi from old
// values -> bitwise-identical to R10 math.
__global__ __launch_bounds__(256) void convex_gather(
    const ushort* __restrict__ xqh, const int* __restrict__ idx,
    float* __restrict__ out) {
  const int tid = threadIdx.x;
  const int l = tid & 63;
  const int w = tid >> 6;
  const int q = l & 3;                                  // lane within row
  const int row = blockIdx.x * 64 + w * 16 + (l >> 2);  // global row

  u32 y[32];
  {
    const uint4* src = reinterpret_cast<const uint4*>(xqh + (size_t)row * 256 + q * 64);
#pragma unroll
    for (int j = 0; j < 8; ++j) {
      uint4 v = src[j];
      y[j * 4 + 0] = v.x; y[j * 4 + 1] = v.y; y[j * 4 + 2] = v.z; y[j * 4 + 3] = v.w;
    }
  }
  const int ii = idx[row];
  const int upIdx = ((l - 1) & 63) * 4;
  const int dnIdx = ((l + 1) & 63) * 4;
  const bool fixP = (q == 0);
  const bool fixN = (q == 3);
  const f16x2 halfc = {(_Float16)0.5f, (_Float16)0.5f};

  // prologue halos: P = prev-lane y[31], N = next-lane y[0]
  u32 P = __builtin_amdgcn_ds_bpermute(upIdx, y[31]);
  u32 N = __builtin_amdgcn_ds_bpermute(dnIdx, y[0]);

  for (int it = 0; it < N_IT; ++it) {
    const u32 Pf = fixP ? 0x7C000000u : P;   // prev.hi = +inf (feat -1 sentinel)
    const u32 Nf = fixN ? 0x00007C00u : N;   // next.lo = +inf (feat 256 sentinel)
    // last reg first (from OLD y[30], y[31]), then first reg; issue next halos
    f16x2 s31 = as_h2(__builtin_amdgcn_alignbit(y[31], y[30], 16));
    f16x2 s32 = as_h2(__builtin_amdgcn_alignbit(Nf, y[31], 16));
    f16x2 s0 = as_h2(__builtin_amdgcn_alignbit(y[0], Pf, 16));
    f16x2 s1 = as_h2(__builtin_amdgcn_alignbit(y[1], y[0], 16));
    y[31] = as_u32(min2(as_h2(y[31]), (s31 + s32) * halfc));
    y[0] = as_u32(min2(as_h2(y[0]), (s0 + s1) * halfc));
    P = __builtin_amdgcn_ds_bpermute(upIdx, y[31]);
    N = __builtin_amdgcn_ds_bpermute(dnIdx, y[0]);
    // interior regs 1..30 from old values; t=30's right stream is saved s31
    f16x2 sp = s1;
#pragma unroll
    for (int t = 1; t < 31; ++t) {
      f16x2 sn = (t == 30) ? s31
                           : as_h2(__builtin_amdgcn_alignbit(y[t + 1], y[t], 16));
      y[t] = as_u32(min2(as_h2(y[t]), (sp + sn) * halfc));
      sp = sn;
    }
  }

  // gather feature ii: 31-cndmask tree over the 32 regs, pick half, cvt, shfl
  const int sel = (ii >> 1) & 31;
#pragma unroll
  for (int step = 16; step >= 1; step >>= 1) {
#pragma unroll
    for (int k = 0; k < 16; ++k) {
      if (k < step) y[k] = (sel & step) ? y[k + step] : y[k];
    }
  }
  ushort hv = (ii & 1) ? (ushort)(y[0] >> 16) : (ushort)(y[0] & 0xffffu);
  float v = (float)__builtin_bit_cast(_Float16, hv);
  v = __shfl(v, (l & ~3) | (ii >> 6));
  if (q == 0) out[row] = v;
}

extern "C" void kernel_launch(void* const* d_in, const int* in_sizes, int n_in,
                              void* d_out, int out_size, void* d_ws, size_t ws_size,
                              hipStream_t stream) {
  const float* x = (const float*)d_in[0];
  const float* W1 = (const float*)d_in[1];
  const float* b1 = (const float*)d_in[2];
  const float* W2 = (const float*)d_in[3];
  const float* b2 = (const float*)d_in[4];
  float* out = (float*)d_out;

  // workspace layout (16B-aligned)
  char* ws = (char*)d_ws;
  ushort* xh  = (ushort*)ws;                    // 16,777,216 B  x f16 [B,256]
  ushort* w1h = (ushort*)(ws + 16777216);       //    524,288 B
  ushort* w2h = (ushort*)(ws + 17301504);       //    524,288 B
  int*    idx = (int*)  (ws + 17825792);        //    131,072 B
  ushort* xqh = (ushort*)(ws + 17956864);       // 16,777,216 B  x_ f16 [B,256]
  ushort* h   = (ushort*)(ws + 34734080);       // chunk*2048 B  h f16 [chunk,1024]

  const size_t fixed = 34734080;
  int chunk = 2048;
  if (ws_size >= fixed + (size_t)32768 * 2048) chunk = 32768;
  else if (ws_size >= fixed + (size_t)16384 * 2048) chunk = 16384;
  else if (ws_size >= fixed + (size_t)8192 * 2048) chunk = 8192;
  else if (ws_size >= fixed + (size_t)4096 * 2048) chunk = 4096;

  prep_kernel<<<8448, 256, 0, stream>>>(x, W1, W2, xh, w1h, w2h, idx);

  for (int m0 = 0; m0 < B_ROWS; m0 += chunk) {
    int curM = (B_ROWS - m0 < chunk) ? (B_ROWS - m0) : chunk;
    dim3 g1((curM / 128) * (N_HID / 128));
    gemm_bt<1><<<g1, 256, 0, stream>>>(xh + (size_t)m0 * 256, w1h, b1, h,
                                       curM, N_HID, N_INP, N_HID / 128);
    dim3 g2((curM / 128) * (NF / 128));
    gemm_bt<0><<<g2, 256, 0, stream>>>(h, w2h, b2, xqh + (size_t)m0 * 256,
                                       curM, NF, N_HID, NF / 128);
  }
  convex_gather<<<B_ROWS / 64, 256, 0, stream>>>(xqh, idx, out);
}

// Round 13
// 132.172 us; speedup vs baseline: 1.1121x; 1.0968x over previous
//
#include <hip/hip_runtime.h>
#include <stdint.h>

#define B_ROWS 32768
#define N_INP 256
#define N_HID 1024
#define NF 256
#define N_IT 100

typedef __attribute__((ext_vector_type(8))) _Float16 f16x8;
typedef __attribute__((ext_vector_type(4))) float f32x4;
typedef __attribute__((ext_vector_type(2))) _Float16 f16x2;
typedef uint32_t u32;

__device__ __forceinline__ ushort f2h(float f) {
  _Float16 h = (_Float16)f;               // v_cvt_f16_f32, RNE
  return *reinterpret_cast<ushort*>(&h);
}

__device__ __forceinline__ void async_copy16(const void* g, void* l) {
  __builtin_amdgcn_global_load_lds(
      (const __attribute__((address_space(1))) void*)g,
      (__attribute__((address_space(3))) void*)l, 16, 0, 0);
}

__device__ __forceinline__ f16x2 as_h2(u32 x) { return __builtin_bit_cast(f16x2, x); }
__device__ __forceinline__ u32 as_u32(f16x2 x) { return __builtin_bit_cast(u32, x); }
// packed f16 min (VOP3P, full rate); single 32-bit regs -> clean regalloc
__device__ __forceinline__ f16x2 min2(f16x2 a, f16x2 b) {
  f16x2 r;
  asm("v_pk_min_f16 %0, %1, %2" : "=v"(r) : "v"(a), "v"(b));
  return r;
}

// ---- prepass (fused): pack x -> f16 [B,256] + idx; convert W1/W2 -> f16 ----
__global__ void prep_kernel(const float* __restrict__ x,
                            const float* __restrict__ W1,
                            const float* __restrict__ W2,
                            ushort* __restrict__ xh,
                            ushort* __restrict__ w1h,
                            ushort* __restrict__ w2h,
                            int* __restrict__ idx) {
  if (blockIdx.x < 8192) {
    int t = blockIdx.x * 256 + threadIdx.x;          // B*64 threads
    int b = t >> 6, q = t & 63;
    const float* xr = x + (size_t)b * (N_INP + 1);
    float v0 = xr[q * 4 + 0], v1 = xr[q * 4 + 1], v2 = xr[q * 4 + 2], v3 = xr[q * 4 + 3];
    ushort4 u = make_ushort4(f2h(v0), f2h(v1), f2h(v2), f2h(v3));
    *reinterpret_cast<ushort4*>(xh + (size_t)b * 256 + q * 4) = u;
    if (q == 0) idx[b] = (int)rintf(xr[N_INP] * 255.0f);
  } else {
    int t = (blockIdx.x - 8192) * 256 + threadIdx.x; // 65536 threads
    float4 a = reinterpret_cast<const float4*>(W1)[t];
    float4 b = reinterpret_cast<const float4*>(W2)[t];
    reinterpret_cast<ushort4*>(w1h)[t] = make_ushort4(f2h(a.x), f2h(a.y), f2h(a.z), f2h(a.w));
    reinterpret_cast<ushort4*>(w2h)[t] = make_ushort4(f2h(b.x), f2h(b.y), f2h(b.z), f2h(b.w));
  }
}

// ---- C[M,N] = epi(A[M,K] @ Bw[N,K]^T + bias), f16 output ----
template <int RELU>
__global__ __launch_bounds__(256, 2) void gemm_bt(
    const ushort* __restrict__ A, const ushort* __restrict__ Bw,
    const float* __restrict__ bias, ushort* __restrict__ C,
    int M, int N, int K, int ntN) {
  __shared__ ushort As[2][128 * 64];
  __shared__ ushort Bs[2][128 * 64];
  const int tid = threadIdx.x;
  const int w = tid >> 6, l = tid & 63;
  // bijective XCD swizzle (grid%8==0 in all our launches)
  int bid = blockIdx.x;
  if (((int)gridDim.x & 7) == 0) {
    int cpx = (int)gridDim.x >> 3;
    bid = (bid & 7) * cpx + (bid >> 3);
  }
  const int tm = bid / ntN, tn = bid % ntN;
  const int wm = w >> 1, wn = w & 1;
  const char* Ab = (const char*)(A + (size_t)tm * 128 * K);
  const char* Bb = (const char*)(Bw + (size_t)tn * 128 * K);
  const int sA = K * 2;
  const int lrow = l >> 3;
  const int lcol = (l & 7) * 16;

  f32x4 acc[4][4];
#pragma unroll
  for (int i = 0; i < 4; ++i)
#pragma unroll
    for (int j = 0; j < 4; ++j) acc[i][j] = {0.f, 0.f, 0.f, 0.f};

  const int nkt = K / 64;
  {
    const char* ga = Ab + lrow * sA + lcol;
    const char* gb = Bb + lrow * sA + lcol;
#pragma unroll
    for (int i = 0; i < 4; ++i) {
      int c = w * 4 + i;
      async_copy16(ga + c * 8 * sA, (char*)&As[0][0] + c * 1024);
      async_copy16(gb + c * 8 * sA, (char*)&Bs[0][0] + c * 1024);
    }
  }
  __syncthreads();

  const int arow = wm * 64 + (l & 15);
  const int brow = wn * 64 + (l & 15);
  const int koff = (l >> 4) * 8;

  for (int kt = 0; kt < nkt; ++kt) {
    const int buf = kt & 1;
    if (kt + 1 < nkt) {
      const char* ga = Ab + (kt + 1) * 128 + lrow * sA + lcol;
      const char* gb = Bb + (kt + 1) * 128 + lrow * sA + lcol;
#pragma unroll
      for (int i = 0; i < 4; ++i) {
        int c = w * 4 + i;
        async_copy16(ga + c * 8 * sA, (char*)&As[buf ^ 1][0] + c * 1024);
        async_copy16(gb + c * 8 * sA, (char*)&Bs[buf ^ 1][0] + c * 1024);
      }
    }
#pragma unroll
    for (int ks = 0; ks < 2; ++ks) {
      f16x8 af[4], bfr[4];
#pragma unroll
      for (int mi = 0; mi < 4; ++mi)
        af[mi] = *(const f16x8*)&As[buf][(arow + mi * 16) * 64 + ks * 32 + koff];
#pragma unroll
      for (int ni = 0; ni < 4; ++ni)
        bfr[ni] = *(const f16x8*)&Bs[buf][(brow + ni * 16) * 64 + ks * 32 + koff];
#pragma unroll
      for (int mi = 0; mi < 4; ++mi)
#pragma unroll
        for (int ni = 0; ni < 4; ++ni)
          acc[mi][ni] = __builtin_amdgcn_mfma_f32_16x16x32_f16(
              af[mi], bfr[ni], acc[mi][ni], 0, 0, 0);
    }
    __syncthreads();
  }

  const int grow0 = tm * 128 + wm * 64 + (l >> 4) * 4;
  const int gcol0 = tn * 128 + wn * 64 + (l & 15);
#pragma unroll
  for (int ni = 0; ni < 4; ++ni) {
    const int col = gcol0 + ni * 16;
    const float bv = bias[col];
#pragma unroll
    for (int mi = 0; mi < 4; ++mi) {
      const int row = grow0 + mi * 16;
#pragma unroll
      for (int r = 0; r < 4; ++r) {
        float v = acc[mi][ni][r] + bv;
        if (RELU) v = fmaxf(v, 0.f);
        C[(size_t)(row + r) * N + col] = f2h(v);
      }
    }
  }
}

// ---- convex fixed-point (100 iters) + gather, PACKED f16, NAMED SCALARS ----
// y_i <- min(y_i, 0.5*(y_{i-1}+y_{i+1})); result = y.
// 8 lanes/row, 32 contiguous feats/lane held in SIXTEEN NAMED u32 scalars
// (w0..w15) -> no array anywhere in the hot loop -> scratch demotion
// impossible (R3/R7/R12 failure mode). 8 rows/wave, grid 1024 blocks.
// Shifted stream via in-lane alignbit; 2 bpermutes/iter serve 8 rows.
// Jacobi from old values; +inf halo sentinels (feats 0,255 never update).
__global__ __launch_bounds__(256) void convex_gather(
    const ushort* __restrict__ xqh, const int* __restrict__ idx,
    float* __restrict__ out) {
  const int tid = threadIdx.x;
  const int l = tid & 63;
  const int wv = tid >> 6;
  const int q = l & 7;                                  // lane within row
  const int row = blockIdx.x * 32 + wv * 8 + (l >> 3);  // global row

  u32 w0, w1, w2, w3, w4, w5, w6, w7, w8, w9, w10, w11, w12, w13, w14, w15;
  {
    const uint4* src = reinterpret_cast<const uint4*>(xqh + (size_t)row * 256 + q * 32);
    uint4 v0 = src[0], v1 = src[1], v2 = src[2], v3 = src[3];
    w0 = v0.x;  w1 = v0.y;  w2 = v0.z;  w3 = v0.w;
    w4 = v1.x;  w5 = v1.y;  w6 = v1.z;  w7 = v1.w;
    w8 = v2.x;  w9 = v2.y;  w10 = v2.z; w11 = v2.w;
    w12 = v3.x; w13 = v3.y; w14 = v3.z; w15 = v3.w;
  }
  const int ii = idx[row];
  const int upIdx = ((l - 1) & 63) * 4;
  const int dnIdx = ((l + 1) & 63) * 4;
  const bool fixP = (q == 0);
  const bool fixN = (q == 7);
  const f16x2 halfc = {(_Float16)0.5f, (_Float16)0.5f};

  // prologue halos: P = prev-lane w15 (f30,f31), N = next-lane w0 (f32,f33)
  u32 P = __builtin_amdgcn_ds_bpermute(upIdx, w15);
  u32 N = __builtin_amdgcn_ds_bpermute(dnIdx, w0);

#define AB(hi, lo) as_h2(__builtin_amdgcn_alignbit((hi), (lo), 16))
#define UPD(wj, sa, sb) wj = as_u32(min2(as_h2(wj), ((sa) + (sb)) * halfc))

#pragma unroll 2
  for (int it = 0; it < N_IT; ++it) {
    const u32 Pf = fixP ? 0x7C000000u : P;   // prev.hi = +inf (feat -1)
    const u32 Nf = fixN ? 0x00007C00u : N;   // next.lo = +inf (feat 256)
    // shifted stream from OLD state: s_j = (f_{2j-1}, f_{2j})
    f16x2 s0 = AB(w0, Pf),  s1 = AB(w1, w0),   s2 = AB(w2, w1),   s3 = AB(w3, w2);
    f16x2 s4 = AB(w4, w3),  s5 = AB(w5, w4),   s6 = AB(w6, w5),   s7 = AB(w7, w6);
    f16x2 s8 = AB(w8, w7),  s9 = AB(w9, w8),   s10 = AB(w10, w9), s11 = AB(w11, w10);
    f16x2 s12 = AB(w12, w11), s13 = AB(w13, w12), s14 = AB(w14, w13), s15 = AB(w15, w14);
    f16x2 s16 = AB(Nf, w15);
    // boundary words first; issue next halos under the interior work
    UPD(w15, s15, s16);
    UPD(w0, s0, s1);
    P = __builtin_amdgcn_ds_bpermute(upIdx, w15);
    N = __builtin_amdgcn_ds_bpermute(dnIdx, w0);
    UPD(w1, s1, s2);   UPD(w2, s2, s3);   UPD(w3, s3, s4);   UPD(w4, s4, s5);
    UPD(w5, s5, s6);   UPD(w6, s6, s7);   UPD(w7, s7, s8);   UPD(w8, s8, s9);
    UPD(w9, s9, s10);  UPD(w10, s10, s11); UPD(w11, s11, s12); UPD(w12, s12, s13);
    UPD(w13, s13, s14); UPD(w14, s14, s15);
  }
#undef AB
#undef UPD

  // gather feature ii: 15-cndmask tree over the 16 named words
  const int sel = (ii >> 1) & 15;
  u32 a0 = (sel & 8) ? w8 : w0,  a1 = (sel & 8) ? w9 : w1;
  u32 a2 = (sel & 8) ? w10 : w2, a3 = (sel & 8) ? w11 : w3;
  u32 a4 = (sel & 8) ? w12 : w4, a5 = (sel & 8) ? w13 : w5;
  u32 a6 = (sel & 8) ? w14 : w6, a7 = (sel & 8) ? w15 : w7;
  u32 b0 = (sel & 4) ? a4 : a0, b1 = (sel & 4) ? a5 : a1;
  u32 b2 = (sel & 4) ? a6 : a2, b3 = (sel & 4) ? a7 : a3;
  u32 c0 = (sel & 2) ? b2 : b0, c1 = (sel & 2) ? b3 : b1;
  u32 d0 = (sel & 1) ? c1 : c0;
  ushort hv = (ii & 1) ? (ushort)(d0 >> 16) : (ushort)(d0 & 0xffffu);
  float v = (float)__builtin_bit_cast(_Float16, hv);
  v = __shfl(v, (l & ~7) | (ii >> 5));
  if (q == 0) out[row] = v;
}

extern "C" void kernel_launch(void* const* d_in, const int* in_sizes, int n_in,
                              void* d_out, int out_size, void* d_ws, size_t ws_size,
                              hipStream_t stream) {
  const float* x = (const float*)d_in[0];
  const float* W1 = (const float*)d_in[1];
  const float* b1 = (const float*)d_in[2];
  const float* W2 = (const float*)d_in[3];
  const float* b2 = (const float*)d_in[4];
  float* out = (float*)d_out;

  // workspace layout (16B-aligned)
  char* ws = (char*)d_ws;
  ushort* xh  = (ushort*)ws;                    // 16,777,216 B  x f16 [B,256]
  ushort* w1h = (ushort*)(ws + 16777216);       //    524,288 B
  ushort* w2h = (ushort*)(ws + 17301504);       //    524,288 B
  int*    idx = (int*)  (ws + 17825792);        //    131,072 B
  ushort* xqh = (ushort*)(ws + 17956864);       // 16,777,216 B  x_ f16 [B,256]
  ushort* h   = (ushort*)(ws + 34734080);       // chunk*2048 B  h f16 [chunk,1024]

  const size_t fixed = 34734080;
  int chunk = 2048;
  if (ws_size >= fixed + (size_t)32768 * 2048) chunk = 32768;
  else if (ws_size >= fixed + (size_t)16384 * 2048) chunk = 16384;
  else if (ws_size >= fixed + (size_t)8192 * 2048) chunk = 8192;
  else if (ws_size >= fixed + (size_t)4096 * 2048) chunk = 4096;

  prep_kernel<<<8448, 256, 0, stream>>>(x, W1, W2, xh, w1h, w2h, idx);

  for (int m0 = 0; m0 < B_ROWS; m0 += chunk) {
    int curM = (B_ROWS - m0 < chunk) ? (B_ROWS - m0) : chunk;
    dim3 g1((curM / 128) * (N_HID / 128));
    gemm_bt<1><<<g1, 256, 0, stream>>>(xh + (size_t)m0 * 256, w1h, b1, h,
                                       curM, N_HID, N_INP, N_HID / 128);
    dim3 g2((curM / 128) * (NF / 128));
    gemm_bt<0><<<g2, 256, 0, stream>>>(h, w2h, b2, xqh + (size_t)m0 * 256,
                                       curM, NF, N_HID, NF / 128);
  }
  convex_gather<<<B_ROWS / 32, 256, 0, stream>>>(xqh, idx, out);
}

// Round 14
// 127.195 us; speedup vs baseline: 1.1556x; 1.0391x over previous
//
#include <hip/hip_runtime.h>
#include <stdint.h>

#define B_ROWS 32768
#define N_INP 256
#define N_HID 1024
#define NF 256
#define N_IT 100

typedef __attribute__((ext_vector_type(8))) _Float16 f16x8;
typedef __attribute__((ext_vector_type(4))) float f32x4;
typedef __attribute__((ext_vector_type(2))) _Float16 f16x2;
typedef uint32_t u32;

__device__ __forceinline__ ushort f2h(float f) {
  _Float16 h = (_Float16)f;               // v_cvt_f16_f32, RNE
  return *reinterpret_cast<ushort*>(&h);
}

__device__ __forceinline__ void async_copy16(const void* g, void* l) {
  __builtin_amdgcn_global_load_lds(
      (const __attribute__((address_space(1))) void*)g,
      (__attribute__((address_space(3))) void*)l, 16, 0, 0);
}

__device__ __forceinline__ f16x2 as_h2(u32 x) { return __builtin_bit_cast(f16x2, x); }
__device__ __forceinline__ u32 as_u32(f16x2 x) { return __builtin_bit_cast(u32, x); }
// packed f16 min (VOP3P, full rate); single 32-bit regs -> clean regalloc
__device__ __forceinline__ f16x2 min2(f16x2 a, f16x2 b) {
  f16x2 r;
  asm("v_pk_min_f16 %0, %1, %2" : "=v"(r) : "v"(a), "v"(b));
  return r;
}

// ---- prepass (fused): pack x -> f16 [B,256] + idx; convert W1/W2 -> f16 ----
__global__ void prep_kernel(const float* __restrict__ x,
                            const float* __restrict__ W1,
                            const float* __restrict__ W2,
                            ushort* __restrict__ xh,
                            ushort* __restrict__ w1h,
                            ushort* __restrict__ w2h,
                            int* __restrict__ idx) {
  if (blockIdx.x < 8192) {
    int t = blockIdx.x * 256 + threadIdx.x;          // B*64 threads
    int b = t >> 6, q = t & 63;
    const float* xr = x + (size_t)b * (N_INP + 1);
    float v0 = xr[q * 4 + 0], v1 = xr[q * 4 + 1], v2 = xr[q * 4 + 2], v3 = xr[q * 4 + 3];
    ushort4 u = make_ushort4(f2h(v0), f2h(v1), f2h(v2), f2h(v3));
    *reinterpret_cast<ushort4*>(xh + (size_t)b * 256 + q * 4) = u;
    if (q == 0) idx[b] = (int)rintf(xr[N_INP] * 255.0f);
  } else {
    int t = (blockIdx.x - 8192) * 256 + threadIdx.x; // 65536 threads
    float4 a = reinterpret_cast<const float4*>(W1)[t];
    float4 b = reinterpret_cast<const float4*>(W2)[t];
    reinterpret_cast<ushort4*>(w1h)[t] = make_ushort4(f2h(a.x), f2h(a.y), f2h(a.z), f2h(a.w));
    reinterpret_cast<ushort4*>(w2h)[t] = make_ushort4(f2h(b.x), f2h(b.y), f2h(b.z), f2h(b.w));
  }
}

// ---- GEMM1: h = relu(xh @ W1^T + b1), f16 output (proven m97 structure) ----
template <int RELU>
__global__ __launch_bounds__(256, 2) void gemm_bt(
    const ushort* __restrict__ A, const ushort* __restrict__ Bw,
    const float* __restrict__ bias, ushort* __restrict__ C,
    int M, int N, int K, int ntN) {
  __shared__ ushort As[2][128 * 64];
  __shared__ ushort Bs[2][128 * 64];
  const int tid = threadIdx.x;
  const int w = tid >> 6, l = tid & 63;
  int bid = blockIdx.x;
  if (((int)gridDim.x & 7) == 0) {
    int cpx = (int)gridDim.x >> 3;
    bid = (bid & 7) * cpx + (bid >> 3);
  }
  const int tm = bid / ntN, tn = bid % ntN;
  const int wm = w >> 1, wn = w & 1;
  const char* Ab = (const char*)(A + (size_t)tm * 128 * K);
  const char* Bb = (const char*)(Bw + (size_t)tn * 128 * K);
  const int sA = K * 2;
  const int lrow = l >> 3;
  const int lcol = (l & 7) * 16;

  f32x4 acc[4][4];
#pragma unroll
  for (int i = 0; i < 4; ++i)
#pragma unroll
    for (int j = 0; j < 4; ++j) acc[i][j] = {0.f, 0.f, 0.f, 0.f};

  const int nkt = K / 64;
  {
    const char* ga = Ab + lrow * sA + lcol;
    const char* gb = Bb + lrow * sA + lcol;
#pragma unroll
    for (int i = 0; i < 4; ++i) {
      int c = w * 4 + i;
      async_copy16(ga + c * 8 * sA, (char*)&As[0][0] + c * 1024);
      async_copy16(gb + c * 8 * sA, (char*)&Bs[0][0] + c * 1024);
    }
  }
  __syncthreads();

  const int arow = wm * 64 + (l & 15);
  const int brow = wn * 64 + (l & 15);
  const int koff = (l >> 4) * 8;

  for (int kt = 0; kt < nkt; ++kt) {
    const int buf = kt & 1;
    if (kt + 1 < nkt) {
      const char* ga = Ab + (kt + 1) * 128 + lrow * sA + lcol;
      const char* gb = Bb + (kt + 1) * 128 + lrow * sA + lcol;
#pragma unroll
      for (int i = 0; i < 4; ++i) {
        int c = w * 4 + i;
        async_copy16(ga + c * 8 * sA, (char*)&As[buf ^ 1][0] + c * 1024);
        async_copy16(gb + c * 8 * sA, (char*)&Bs[buf ^ 1][0] + c * 1024);
      }
    }
#pragma unroll
    for (int ks = 0; ks < 2; ++ks) {
      f16x8 af[4], bfr[4];
#pragma unroll
      for (int mi = 0; mi < 4; ++mi)
        af[mi] = *(const f16x8*)&As[buf][(arow + mi * 16) * 64 + ks * 32 + koff];
#pragma unroll
      for (int ni = 0; ni < 4; ++ni)
        bfr[ni] = *(const f16x8*)&Bs[buf][(brow + ni * 16) * 64 + ks * 32 + koff];
#pragma unroll
      for (int mi = 0; mi < 4; ++mi)
#pragma unroll
        for (int ni = 0; ni < 4; ++ni)
          acc[mi][ni] = __builtin_amdgcn_mfma_f32_16x16x32_f16(
              af[mi], bfr[ni], acc[mi][ni], 0, 0, 0);
    }
    __syncthreads();
  }

  const int grow0 = tm * 128 + wm * 64 + (l >> 4) * 4;
  const int gcol0 = tn * 128 + wn * 64 + (l & 15);
#pragma unroll
  for (int ni = 0; ni < 4; ++ni) {
    const int col = gcol0 + ni * 16;
    const float bv = bias[col];
#pragma unroll
    for (int mi = 0; mi < 4; ++mi) {
      const int row = grow0 + mi * 16;
#pragma unroll
      for (int r = 0; r < 4; ++r) {
        float v = acc[mi][ni][r] + bv;
        if (RELU) v = fmaxf(v, 0.f);
        C[(size_t)(row + r) * N + col] = f2h(v);
      }
    }
  }
}

// ---- FUSED GEMM2 + convex + gather. 64 rows/block, 1024 thr (16 waves).
// LDS 40KB: As 2x[64][32] f16 (8K) + Bs 2x[256][32] f16 (32K); after the
// K-loop the f16 x_ tile [64][256] (32K) aliases the staging area.
// 40KB + 16 waves -> 2 blocks/CU (32 waves) -- the occupancy R8 lacked.
// Convex phase: R13's named-scalar packed-f16 iteration, 16 lanes/row,
// 8 words/lane, at 8 waves/SIMD; co-schedules with other block's MFMA phase.
__global__ __launch_bounds__(1024, 8) void gemm2_convex(
    const ushort* __restrict__ A,      // h chunk [curM][1024] f16
    const ushort* __restrict__ Bw,     // w2h [256][1024] f16
    const float* __restrict__ bias,    // b2 [256] f32
    const int* __restrict__ idxp,      // idx + m0
    float* __restrict__ out) {         // out + m0
  __shared__ ushort smem[20480];       // 40960 B
  const int tid = threadIdx.x;
  const int w = tid >> 6, l = tid & 63;
  const int wm = w >> 2, wn = w & 3;   // 4x4 wave grid
  const int m0r = blockIdx.x * 64;

  f32x4 acc[4];
#pragma unroll
  for (int i = 0; i < 4; ++i) acc[i] = {0.f, 0.f, 0.f, 0.f};

  const int srow = tid >> 2, sc = tid & 3;          // staging coords
  const ushort* gA = A + (size_t)(m0r + srow) * N_HID + sc * 8;
  const ushort* gB = Bw + (size_t)srow * N_HID + sc * 8;

#define STAGE(kt, buf)                                                  \
  {                                                                     \
    if (tid < 256) async_copy16(gA + (kt) * 32, smem + (buf) * 2048 + tid * 8); \
    async_copy16(gB + (kt) * 32, smem + 4096 + (buf) * 8192 + tid * 8); \
  }

  STAGE(0, 0);
  __syncthreads();

  const int arow = wm * 16 + (l & 15);
  const int koff = (l >> 4) * 8;
  const int brow0 = wn * 64 + (l & 15);

  for (int kt = 0; kt < 32; ++kt) {
    const int buf = kt & 1;
    if (kt < 31) STAGE(kt + 1, buf ^ 1);
    f16x8 af = *(const f16x8*)(smem + buf * 2048 + arow * 32 + koff);
#pragma unroll
    for (int ni = 0; ni < 4; ++ni) {
      f16x8 bf = *(const f16x8*)(smem + 4096 + buf * 8192 + (brow0 + ni * 16) * 32 + koff);
      acc[ni] = __builtin_amdgcn_mfma_f32_16x16x32_f16(af, bf, acc[ni], 0, 0, 0);
    }
    __syncthreads();
  }
#undef STAGE

  // epilogue: x_ tile -> f16 in LDS (aliases staging; all reads barrier-done)
  {
    const int r0 = wm * 16 + (l >> 4) * 4;
    const int c0 = wn * 64 + (l & 15);
#pragma unroll
    for (int ni = 0; ni < 4; ++ni) {
      const int col = c0 + ni * 16;
      const float bv = bias[col];
#pragma unroll
      for (int r = 0; r < 4; ++r)
        smem[(r0 + r) * 256 + col] = f2h(acc[ni][r] + bv);
    }
  }
  __syncthreads();

  // ---- convex: 16 lanes/row, 16 feats/lane in 8 NAMED u32 words ----
  const int q = l & 15;
  const int row = w * 4 + (l >> 4);        // 0..63
  u32 w0, w1, w2, w3, w4, w5, w6, w7;
  {
    const uint4* src = reinterpret_cast<const uint4*>(smem + row * 256 + q * 16);
    uint4 v0 = src[0], v1 = src[1];
    w0 = v0.x; w1 = v0.y; w2 = v0.z; w3 = v0.w;
    w4 = v1.x; w5 = v1.y; w6 = v1.z; w7 = v1.w;
  }
  const int ii = idxp[m0r + row];
  const int upIdx = ((l - 1) & 63) * 4;
  const int dnIdx = ((l + 1) & 63) * 4;
  const bool fixP = (q == 0);
  const bool fixN = (q == 15);
  const f16x2 halfc = {(_Float16)0.5f, (_Float16)0.5f};

  u32 P = __builtin_amdgcn_ds_bpermute(upIdx, w7);
  u32 N = __builtin_amdgcn_ds_bpermute(dnIdx, w0);

#define AB(hi, lo) as_h2(__builtin_amdgcn_alignbit((hi), (lo), 16))
#define UPD(wj, sa, sb) wj = as_u32(min2(as_h2(wj), ((sa) + (sb)) * halfc))
#pragma unroll 2
  for (int it = 0; it < N_IT; ++it) {
    const u32 Pf = fixP ? 0x7C000000u : P;   // prev.hi = +inf (feat -1)
    const u32 Nf = fixN ? 0x00007C00u : N;   // next.lo = +inf (feat 256)
    f16x2 s0 = AB(w0, Pf), s1 = AB(w1, w0), s2 = AB(w2, w1), s3 = AB(w3, w2);
    f16x2 s4 = AB(w4, w3), s5 = AB(w5, w4), s6 = AB(w6, w5), s7 = AB(w7, w6);
    f16x2 s8 = AB(Nf, w7);
    UPD(w7, s7, s8);
    UPD(w0, s0, s1);
    P = __builtin_amdgcn_ds_bpermute(upIdx, w7);
    N = __builtin_amdgcn_ds_bpermute(dnIdx, w0);
    UPD(w1, s1, s2); UPD(w2, s2, s3); UPD(w3, s3, s4);
    UPD(w4, s4, s5); UPD(w5, s5, s6); UPD(w6, s6, s7);
  }
#undef AB
#undef UPD

  // gather feature ii: 7-cndmask tree over 8 words, half pick, cvt, shfl
  const int sel = (ii >> 1) & 7;
  u32 a0 = (sel & 4) ? w4 : w0, a1 = (sel & 4) ? w5 : w1;
  u32 a2 = (sel & 4) ? w6 : w2, a3 = (sel & 4) ? w7 : w3;
  u32 b0 = (sel & 2) ? a2 : a0, b1 = (sel & 2) ? a3 : a1;
  u32 c0 = (sel & 1) ? b1 : b0;
  ushort hv = (ii & 1) ? (ushort)(c0 >> 16) : (ushort)(c0 & 0xffffu);
  float v = (float)__builtin_bit_cast(_Float16, hv);
  v = __shfl(v, (l & ~15) | (ii >> 4));
  if (q == 0) out[m0r + row] = v;
}

extern "C" void kernel_launch(void* const* d_in, const int* in_sizes, int n_in,
                              void* d_out, int out_size, void* d_ws, size_t ws_size,
                              hipStream_t stream) {
  const float* x = (const float*)d_in[0];
  const float* W1 = (const float*)d_in[1];
  const float* b1 = (const float*)d_in[2];
  const float* W2 = (const float*)d_in[3];
  const float* b2 = (const float*)d_in[4];
  float* out = (float*)d_out;

  // workspace layout (16B-aligned)
  char* ws = (char*)d_ws;
  ushort* xh  = (ushort*)ws;                    // 16,777,216 B  x f16 [B,256]
  ushort* w1h = (ushort*)(ws + 16777216);       //    524,288 B
  ushort* w2h = (ushort*)(ws + 17301504);       //    524,288 B
  int*    idx = (int*)  (ws + 17825792);        //    131,072 B
  ushort* h   = (ushort*)(ws + 17956864);       // chunk*2048 B  h f16 [chunk,1024]

  const size_t fixed = 17956864;
  int chunk = 2048;
  if (ws_size >= fixed + (size_t)32768 * 2048) chunk = 32768;
  else if (ws_size >= fixed + (size_t)16384 * 2048) chunk = 16384;
  else if (ws_size >= fixed + (size_t)8192 * 2048) chunk = 8192;
  else if (ws_size >= fixed + (size_t)4096 * 2048) chunk = 4096;

  prep_kernel<<<8448, 256, 0, stream>>>(x, W1, W2, xh, w1h, w2h, idx);

  for (int m0 = 0; m0 < B_ROWS; m0 += chunk) {
    int curM = (B_ROWS - m0 < chunk) ? (B_ROWS - m0) : chunk;
    dim3 g1((curM / 128) * (N_HID / 128));
    gemm_bt<1><<<g1, 256, 0, stream>>>(xh + (size_t)m0 * 256, w1h, b1, h,
                                       curM, N_HID, N_INP, N_HID / 128);
    gemm2_convex<<<curM / 64, 1024, 0, stream>>>(h, w2h, b2, idx + m0, out + m0);
  }
}

// Round 15
// 125.387 us; speedup vs baseline: 1.1722x; 1.0144x over previous
//
#include <hip/hip_runtime.h>
#include <stdint.h>

#define B_ROWS 32768
#define N_INP 256
#define N_HID 1024
#define NF 256
#define N_IT 100

typedef __attribute__((ext_vector_type(8))) _Float16 f16x8;
typedef __attribute__((ext_vector_type(4))) float f32x4;
typedef __attribute__((ext_vector_type(2))) _Float16 f16x2;
typedef uint32_t u32;

__device__ __forceinline__ ushort f2h(float f) {
  _Float16 h = (_Float16)f;               // v_cvt_f16_f32, RNE
  return *reinterpret_cast<ushort*>(&h);
}

__device__ __forceinline__ void async_copy16(const void* g, void* l) {
  __builtin_amdgcn_global_load_lds(
      (const __attribute__((address_space(1))) void*)g,
      (__attribute__((address_space(3))) void*)l, 16, 0, 0);
}

__device__ __forceinline__ f16x2 as_h2(u32 x) { return __builtin_bit_cast(f16x2, x); }
__device__ __forceinline__ u32 as_u32(f16x2 x) { return __builtin_bit_cast(u32, x); }
// packed f16 min (VOP3P, full rate); single 32-bit regs -> clean regalloc
__device__ __forceinline__ f16x2 min2(f16x2 a, f16x2 b) {
  f16x2 r;
  asm("v_pk_min_f16 %0, %1, %2" : "=v"(r) : "v"(a), "v"(b));
  return r;
}

// ---- prepass (fused): pack x -> f16 [B,256] + idx; convert W1/W2 -> f16 ----
__global__ void prep_kernel(const float* __restrict__ x,
                            const float* __restrict__ W1,
                            const float* __restrict__ W2,
                            ushort* __restrict__ xh,
                            ushort* __restrict__ w1h,
                            ushort* __restrict__ w2h,
                            int* __restrict__ idx) {
  if (blockIdx.x < 8192) {
    int t = blockIdx.x * 256 + threadIdx.x;          // B*64 threads
    int b = t >> 6, q = t & 63;
    const float* xr = x + (size_t)b * (N_INP + 1);
    float v0 = xr[q * 4 + 0], v1 = xr[q * 4 + 1], v2 = xr[q * 4 + 2], v3 = xr[q * 4 + 3];
    ushort4 u = make_ushort4(f2h(v0), f2h(v1), f2h(v2), f2h(v3));
    *reinterpret_cast<ushort4*>(xh + (size_t)b * 256 + q * 4) = u;
    if (q == 0) idx[b] = (int)rintf(xr[N_INP] * 255.0f);
  } else {
    int t = (blockIdx.x - 8192) * 256 + threadIdx.x; // 65536 threads
    float4 a = reinterpret_cast<const float4*>(W1)[t];
    float4 b = reinterpret_cast<const float4*>(W2)[t];
    reinterpret_cast<ushort4*>(w1h)[t] = make_ushort4(f2h(a.x), f2h(a.y), f2h(a.z), f2h(a.w));
    reinterpret_cast<ushort4*>(w2h)[t] = make_ushort4(f2h(b.x), f2h(b.y), f2h(b.z), f2h(b.w));
  }
}

// ---- GEMM1: h = relu(xh @ W1^T + b1), f16 output (proven m97 structure) ----
template <int RELU>
__global__ __launch_bounds__(256, 2) void gemm_bt(
    const ushort* __restrict__ A, const ushort* __restrict__ Bw,
    const float* __restrict__ bias, ushort* __restrict__ C,
    int M, int N, int K, int ntN) {
  __shared__ ushort As[2][128 * 64];
  __shared__ ushort Bs[2][128 * 64];
  const int tid = threadIdx.x;
  const int w = tid >> 6, l = tid & 63;
  int bid = blockIdx.x;
  if (((int)gridDim.x & 7) == 0) {
    int cpx = (int)gridDim.x >> 3;
    bid = (bid & 7) * cpx + (bid >> 3);
  }
  const int tm = bid / ntN, tn = bid % ntN;
  const int wm = w >> 1, wn = w & 1;
  const char* Ab = (const char*)(A + (size_t)tm * 128 * K);
  const char* Bb = (const char*)(Bw + (size_t)tn * 128 * K);
  const int sA = K * 2;
  const int lrow = l >> 3;
  const int lcol = (l & 7) * 16;

  f32x4 acc[4][4];
#pragma unroll
  for (int i = 0; i < 4; ++i)
#pragma unroll
    for (int j = 0; j < 4; ++j) acc[i][j] = {0.f, 0.f, 0.f, 0.f};

  const int nkt = K / 64;
  {
    const char* ga = Ab + lrow * sA + lcol;
    const char* gb = Bb + lrow * sA + lcol;
#pragma unroll
    for (int i = 0; i < 4; ++i) {
      int c = w * 4 + i;
      async_copy16(ga + c * 8 * sA, (char*)&As[0][0] + c * 1024);
      async_copy16(gb + c * 8 * sA, (char*)&Bs[0][0] + c * 1024);
    }
  }
  __syncthreads();

  const int arow = wm * 64 + (l & 15);
  const int brow = wn * 64 + (l & 15);
  const int koff = (l >> 4) * 8;

  for (int kt = 0; kt < nkt; ++kt) {
    const int buf = kt & 1;
    if (kt + 1 < nkt) {
      const char* ga = Ab + (kt + 1) * 128 + lrow * sA + lcol;
      const char* gb = Bb + (kt + 1) * 128 + lrow * sA + lcol;
#pragma unroll
      for (int i = 0; i < 4; ++i) {
        int c = w * 4 + i;
        async_copy16(ga + c * 8 * sA, (char*)&As[buf ^ 1][0] + c * 1024);
        async_copy16(gb + c * 8 * sA, (char*)&Bs[buf ^ 1][0] + c * 1024);
      }
    }
#pragma unroll
    for (int ks = 0; ks < 2; ++ks) {
      f16x8 af[4], bfr[4];
#pragma unroll
      for (int mi = 0; mi < 4; ++mi)
        af[mi] = *(const f16x8*)&As[buf][(arow + mi * 16) * 64 + ks * 32 + koff];
#pragma unroll
      for (int ni = 0; ni < 4; ++ni)
        bfr[ni] = *(const f16x8*)&Bs[buf][(brow + ni * 16) * 64 + ks * 32 + koff];
#pragma unroll
      for (int mi = 0; mi < 4; ++mi)
#pragma unroll
        for (int ni = 0; ni < 4; ++ni)
          acc[mi][ni] = __builtin_amdgcn_mfma_f32_16x16x32_f16(
              af[mi], bfr[ni], acc[mi][ni], 0, 0, 0);
    }
    __syncthreads();
  }

  const int grow0 = tm * 128 + wm * 64 + (l >> 4) * 4;
  const int gcol0 = tn * 128 + wn * 64 + (l & 15);
#pragma unroll
  for (int ni = 0; ni < 4; ++ni) {
    const int col = gcol0 + ni * 16;
    const float bv = bias[col];
#pragma unroll
    for (int mi = 0; mi < 4; ++mi) {
      const int row = grow0 + mi * 16;
#pragma unroll
      for (int r = 0; r < 4; ++r) {
        float v = acc[mi][ni][r] + bv;
        if (RELU) v = fmaxf(v, 0.f);
        C[(size_t)(row + r) * N + col] = f2h(v);
      }
    }
  }
}

// ---- FUSED GEMM2 + convex + gather. 64 rows/block, 1024 thr (16 waves).
// LDS 40KB: As 2x[64][32] f16 (8K) + Bs 2x[256][32] f16 (32K); x_ f16 tile
// [64][256] (32K) aliases staging after the K-loop. 2 blocks/CU, 32 waves/CU.
// T2 swizzle (rule #21, both-sides): staging SOURCE chunk is inverse-XOR'd
// (sc ^= (srow>>1)&3, an involution; gload_lds dest stays linear) and reads
// XOR the chunk the same way -> 16-lane fragment reads spread over 8 banks
// (2 lanes/bank = free) instead of ~8-way aliasing.
__global__ __launch_bounds__(1024, 8) void gemm2_convex(
    const ushort* __restrict__ A,      // h chunk [curM][1024] f16
    const ushort* __restrict__ Bw,     // w2h [256][1024] f16
    const float* __restrict__ bias,    // b2 [256] f32
    const int* __restrict__ idxp,      // idx + m0
    float* __restrict__ out) {         // out + m0
  __shared__ ushort smem[20480];       // 40960 B
  const int tid = threadIdx.x;
  const int w = tid >> 6, l = tid & 63;
  const int wm = w >> 2, wn = w & 3;   // 4x4 wave grid
  const int m0r = blockIdx.x * 64;

  f32x4 acc[4];
#pragma unroll
  for (int i = 0; i < 4; ++i) acc[i] = {0.f, 0.f, 0.f, 0.f};

  const int srow = tid >> 2;                        // staging row
  const int scs = (tid & 3) ^ ((srow >> 1) & 3);    // inverse-swizzled src chunk
  const ushort* gA = A + (size_t)(m0r + srow) * N_HID + scs * 8;
  const ushort* gB = Bw + (size_t)srow * N_HID + scs * 8;

#define STAGE(kt, buf)                                                  \
  {                                                                     \
    if (tid < 256) async_copy16(gA + (kt) * 32, smem + (buf) * 2048 + tid * 8); \
    async_copy16(gB + (kt) * 32, smem + 4096 + (buf) * 8192 + tid * 8); \
  }

  STAGE(0, 0);
  __syncthreads();

  const int arow = wm * 16 + (l & 15);
  const int brow0 = wn * 64 + (l & 15);
  // read-side swizzled K-chunk: chunk = (l>>4) ^ ((row>>1)&3); row's low
  // swizzle bits equal (l>>1)&3 for both A (wm*16) and B (wn*64+ni*16).
  const int kx = (((l >> 4) ^ ((l >> 1) & 3)) * 8);

  for (int kt = 0; kt < 32; ++kt) {
    const int buf = kt & 1;
    if (kt < 31) STAGE(kt + 1, buf ^ 1);
    f16x8 af = *(const f16x8*)(smem + buf * 2048 + arow * 32 + kx);
#pragma unroll
    for (int ni = 0; ni < 4; ++ni) {
      f16x8 bf = *(const f16x8*)(smem + 4096 + buf * 8192 + (brow0 + ni * 16) * 32 + kx);
      acc[ni] = __builtin_amdgcn_mfma_f32_16x16x32_f16(af, bf, acc[ni], 0, 0, 0);
    }
    __syncthreads();
  }
#undef STAGE

  // epilogue: x_ tile -> f16 in LDS (aliases staging; all reads barrier-done)
  {
    const int r0 = wm * 16 + (l >> 4) * 4;
    const int c0 = wn * 64 + (l & 15);
#pragma unroll
    for (int ni = 0; ni < 4; ++ni) {
      const int col = c0 + ni * 16;
      const float bv = bias[col];
#pragma unroll
      for (int r = 0; r < 4; ++r)
        smem[(r0 + r) * 256 + col] = f2h(acc[ni][r] + bv);
    }
  }
  __syncthreads();

  // ---- convex: 16 lanes/row, 16 feats/lane in 8 NAMED u32 words ----
  const int q = l & 15;
  const int row = w * 4 + (l >> 4);        // 0..63
  u32 w0, w1, w2, w3, w4, w5, w6, w7;
  {
    const uint4* src = reinterpret_cast<const uint4*>(smem + row * 256 + q * 16);
    uint4 v0 = src[0], v1 = src[1];
    w0 = v0.x; w1 = v0.y; w2 = v0.z; w3 = v0.w;
    w4 = v1.x; w5 = v1.y; w6 = v1.z; w7 = v1.w;
  }
  const int ii = idxp[m0r + row];
  const int upIdx = ((l - 1) & 63) * 4;
  const int dnIdx = ((l + 1) & 63) * 4;
  const bool fixP = (q == 0);
  const bool fixN = (q == 15);
  const f16x2 halfc = {(_Float16)0.5f, (_Float16)0.5f};

  u32 P = __builtin_amdgcn_ds_bpermute(upIdx, w7);
  u32 N = __builtin_amdgcn_ds_bpermute(dnIdx, w0);

#define AB(hi, lo) as_h2(__builtin_amdgcn_alignbit((hi), (lo), 16))
#define UPD(wj, sa, sb) wj = as_u32(min2(as_h2(wj), ((sa) + (sb)) * halfc))
#pragma unroll 2
  for (int it = 0; it < N_IT; ++it) {
    const u32 Pf = fixP ? 0x7C000000u : P;   // prev.hi = +inf (feat -1)
    const u32 Nf = fixN ? 0x00007C00u : N;   // next.lo = +inf (feat 256)
    f16x2 s0 = AB(w0, Pf), s1 = AB(w1, w0), s2 = AB(w2, w1), s3 = AB(w3, w2);
    f16x2 s4 = AB(w4, w3), s5 = AB(w5, w4), s6 = AB(w6, w5), s7 = AB(w7, w6);
    f16x2 s8 = AB(Nf, w7);
    UPD(w7, s7, s8);
    UPD(w0, s0, s1);
    P = __builtin_amdgcn_ds_bpermute(upIdx, w7);
    N = __builtin_amdgcn_ds_bpermute(dnIdx, w0);
    UPD(w1, s1, s2); UPD(w2, s2, s3); UPD(w3, s3, s4);
    UPD(w4, s4, s5); UPD(w5, s5, s6); UPD(w6, s6, s7);
  }
#undef AB
#undef UPD

  // gather feature ii: 7-cndmask tree over 8 words, half pick, cvt, shfl
  const int sel = (ii >> 1) & 7;
  u32 a0 = (sel & 4) ? w4 : w0, a1 = (sel & 4) ? w5 : w1;
  u32 a2 = (sel & 4) ? w6 : w2, a3 = (sel & 4) ? w7 : w3;
  u32 b0 = (sel & 2) ? a2 : a0, b1 = (sel & 2) ? a3 : a1;
  u32 c0 = (sel & 1) ? b1 : b0;
  ushort hv = (ii & 1) ? (ushort)(c0 >> 16) : (ushort)(c0 & 0xffffu);
  float v = (float)__builtin_bit_cast(_Float16, hv);
  v = __shfl(v, (l & ~15) | (ii >> 4));
  if (q == 0) out[m0r + row] = v;
}

extern "C" void kernel_launch(void* const* d_in, const int* in_sizes, int n_in,
                              void* d_out, int out_size, void* d_ws, size_t ws_size,
                              hipStream_t stream) {
  const float* x = (const float*)d_in[0];
  const float* W1 = (const float*)d_in[1];
  const float* b1 = (const float*)d_in[2];
  const float* W2 = (const float*)d_in[3];
  const float* b2 = (const float*)d_in[4];
  float* out = (float*)d_out;

  // workspace layout (16B-aligned)
  char* ws = (char*)d_ws;
  ushort* xh  = (ushort*)ws;                    // 16,777,216 B  x f16 [B,256]
  ushort* w1h = (ushort*)(ws + 16777216);       //    524,288 B
  ushort* w2h = (ushort*)(ws + 17301504);       //    524,288 B
  int*    idx = (int*)  (ws + 17825792);        //    131,072 B
  ushort* h   = (ushort*)(ws + 17956864);       // chunk*2048 B  h f16 [chunk,1024]

  const size_t fixed = 17956864;
  int chunk = 2048;
  if (ws_size >= fixed + (size_t)32768 * 2048) chunk = 32768;
  else if (ws_size >= fixed + (size_t)16384 * 2048) chunk = 16384;
  else if (ws_size >= fixed + (size_t)8192 * 2048) chunk = 8192;
  else if (ws_size >= fixed + (size_t)4096 * 2048) chunk = 4096;

  prep_kernel<<<8448, 256, 0, stream>>>(x, W1, W2, xh, w1h, w2h, idx);

  for (int m0 = 0; m0 < B_ROWS; m0 += chunk) {
    int curM = (B_ROWS - m0 < chunk) ? (B_ROWS - m0) : chunk;
    dim3 g1((curM / 128) * (N_HID / 128));
    gemm_bt<1><<<g1, 256, 0, stream>>>(xh + (size_t)m0 * 256, w1h, b1, h,
                                       curM, N_HID, N_INP, N_HID / 128);
    gemm2_convex<<<curM / 64, 1024, 0, stream>>>(h, w2h, b2, idx + m0, out + m0);
  }
}

// Round 16
// 122.545 us; speedup vs baseline: 1.1994x; 1.0232x over previous
//
#include <hip/hip_runtime.h>
#include <stdint.h>

#define B_ROWS 32768
#define N_INP 256
#define N_HID 1024
#define NF 256
#define N_IT 100

typedef __attribute__((ext_vector_type(8))) _Float16 f16x8;
typedef __attribute__((ext_vector_type(4))) float f32x4;
typedef __attribute__((ext_vector_type(2))) _Float16 f16x2;
typedef float f32x4a __attribute__((ext_vector_type(4), aligned(4)));  // 4B-aligned vec load
typedef uint32_t u32;

__device__ __forceinline__ ushort f2h(float f) {
  _Float16 h = (_Float16)f;               // v_cvt_f16_f32, RNE
  return *reinterpret_cast<ushort*>(&h);
}

// pack two f32 -> two f16 (RNE) in one u32 (v_cvt_f16_f32 x2 + v_pack_b32_f16)
__device__ __forceinline__ u32 pkh(float a, float b) {
  _Float16 ha = (_Float16)a, hb = (_Float16)b;
  return (u32)*reinterpret_cast<ushort*>(&ha) |
         ((u32)*reinterpret_cast<ushort*>(&hb) << 16);
}

__device__ __forceinline__ void async_copy16(const void* g, void* l) {
  __builtin_amdgcn_global_load_lds(
      (const __attribute__((address_space(1))) void*)g,
      (__attribute__((address_space(3))) void*)l, 16, 0, 0);
}

__device__ __forceinline__ f16x2 as_h2(u32 x) { return __builtin_bit_cast(f16x2, x); }
__device__ __forceinline__ u32 as_u32(f16x2 x) { return __builtin_bit_cast(u32, x); }
__device__ __forceinline__ f16x2 min2(f16x2 a, f16x2 b) {
  f16x2 r;
  asm("v_pk_min_f16 %0, %1, %2" : "=v"(r) : "v"(a), "v"(b));
  return r;
}

// ---- prepass (small): convert W1/W2 -> f16; extract idx ----
// blocks [0,256): weights; blocks [256,384): idx
__global__ void prep_kernel(const float* __restrict__ x,
                            const float* __restrict__ W1,
                            const float* __restrict__ W2,
                            ushort* __restrict__ w1h,
                            ushort* __restrict__ w2h,
                            int* __restrict__ idx) {
  if (blockIdx.x < 256) {
    int t = blockIdx.x * 256 + threadIdx.x;          // 65536 threads
    float4 a = reinterpret_cast<const float4*>(W1)[t];
    float4 b = reinterpret_cast<const float4*>(W2)[t];
    reinterpret_cast<ushort4*>(w1h)[t] = make_ushort4(f2h(a.x), f2h(a.y), f2h(a.z), f2h(a.w));
    reinterpret_cast<ushort4*>(w2h)[t] = make_ushort4(f2h(b.x), f2h(b.y), f2h(b.z), f2h(b.w));
  } else {
    int r = (blockIdx.x - 256) * 256 + threadIdx.x;  // 32768 rows
    idx[r] = (int)rintf(x[(size_t)r * 257 + 256] * 255.0f);
  }
}

// ---- GEMM1 with fused x->f16 conversion: h = relu(f16(x[:, :256]) @ W1^T + b1)
// A staged from f32 x via regs (load f32 -> cvt RNE -> pack -> ds_write_b128,
// lane-linear dest = conflict-free); B (w1h) via global_load_lds. 128x128 tile,
// BK=64, 4 K-steps. Loads for kt+1 issued before MFMA(kt), cvt+write after
// (T14 issue-early/write-late: HBM latency hides under MFMA).
__global__ __launch_bounds__(256) void gemm1_x(
    const float* __restrict__ X,       // [M,257] f32 (chunk base)
    const ushort* __restrict__ Bw,     // w1h [1024][256] f16
    const float* __restrict__ bias,    // b1
    ushort* __restrict__ C,            // h [M,1024] f16
    int ntN) {
  __shared__ ushort As[2][128 * 64];
  __shared__ ushort Bs[2][128 * 64];
  const int t = threadIdx.x;
  const int w = t >> 6, l = t & 63;
  int bid = blockIdx.x;
  if (((int)gridDim.x & 7) == 0) {
    int cpx = (int)gridDim.x >> 3;
    bid = (bid & 7) * cpx + (bid >> 3);
  }
  const int tm = bid / ntN, tn = bid % ntN;
  const int wm = w >> 1, wn = w & 1;

  const float* Xb = X + (size_t)(tm * 128) * 257;
  const char* Bb = (const char*)(Bw + (size_t)tn * 128 * 256);
  const int sB = 512;                 // B row stride bytes (K=256 f16)
  const int lrow = l >> 3;
  const int lcol = (l & 7) * 16;

  // A staging coords: thread t covers rows ar0+{0,32,64,96}, k-floats ak0..ak0+7
  const int ar0 = t >> 3;
  const int ak0 = (t & 7) * 8;

  f32x4a a0, a1, a2, a3, a4, a5, a6, a7;
#define LOADA(kt)                                                        \
  {                                                                      \
    const float* p0 = Xb + (size_t)ar0 * 257 + (kt) * 64 + ak0;          \
    const float* p1 = p0 + (size_t)32 * 257;                             \
    const float* p2 = p0 + (size_t)64 * 257;                             \
    const float* p3 = p0 + (size_t)96 * 257;                             \
    a0 = *(const f32x4a*)p0; a1 = *(const f32x4a*)(p0 + 4);              \
    a2 = *(const f32x4a*)p1; a3 = *(const f32x4a*)(p1 + 4);              \
    a4 = *(const f32x4a*)p2; a5 = *(const f32x4a*)(p2 + 4);              \
    a6 = *(const f32x4a*)p3; a7 = *(const f32x4a*)(p3 + 4);              \
  }
#define WRITEA(buf)                                                      \
  {                                                                      \
    uint4* d = (uint4*)((char*)&As[buf][0] + t * 16);                    \
    d[0]   = make_uint4(pkh(a0.x, a0.y), pkh(a0.z, a0.w),                \
                        pkh(a1.x, a1.y), pkh(a1.z, a1.w));               \
    d[256] = make_uint4(pkh(a2.x, a2.y), pkh(a2.z, a2.w),                \
                        pkh(a3.x, a3.y), pkh(a3.z, a3.w));               \
    d[512] = make_uint4(pkh(a4.x, a4.y), pkh(a4.z, a4.w),                \
                        pkh(a5.x, a5.y), pkh(a5.z, a5.w));               \
    d[768] = make_uint4(pkh(a6.x, a6.y), pkh(a6.z, a6.w),                \
                        pkh(a7.x, a7.y), pkh(a7.z, a7.w));               \
  }
#define STAGEB(kt, buf)                                                  \
  {                                                                      \
    const char* gb = Bb + lrow * sB + (kt) * 128 + lcol;                 \
    _Pragma("unroll") for (int i = 0; i < 4; ++i) {                      \
      int c = w * 4 + i;                                                 \
      async_copy16(gb + c * 8 * sB, (char*)&Bs[buf][0] + c * 1024);      \
    }                                                                    \
  }

  f32x4 acc[4][4];
#pragma unroll
  for (int i = 0; i < 4; ++i)
#pragma unroll
    for (int j = 0; j < 4; ++j) acc[i][j] = {0.f, 0.f, 0.f, 0.f};

  LOADA(0);
  STAGEB(0, 0);
  WRITEA(0);
  __syncthreads();

  const int arow = wm * 64 + (l & 15);
  const int brow = wn * 64 + (l & 15);
  const int koff = (l >> 4) * 8;

  for (int kt = 0; kt < 4; ++kt) {
    const int buf = kt & 1;
    if (kt < 3) {
      LOADA(kt + 1);
      STAGEB(kt + 1, buf ^ 1);
    }
#pragma unroll
    for (int ks = 0; ks < 2; ++ks) {
      f16x8 af[4], bfr[4];
#pragma unroll
      for (int mi = 0; mi < 4; ++mi)
        af[mi] = *(const f16x8*)&As[buf][(arow + mi * 16) * 64 + ks * 32 + koff];
#pragma unroll
      for (int ni = 0; ni < 4; ++ni)
        bfr[ni] = *(const f16x8*)&Bs[buf][(brow + ni * 16) * 64 + ks * 32 + koff];
#pragma unroll
      for (int mi = 0; mi < 4; ++mi)
#pragma unroll
        for (int ni = 0; ni < 4; ++ni)
          acc[mi][ni] = __builtin_amdgcn_mfma_f32_16x16x32_f16(
              af[mi], bfr[ni], acc[mi][ni], 0, 0, 0);
    }
    if (kt < 3) WRITEA(buf ^ 1);
    __syncthreads();
  }
#undef LOADA
#undef WRITEA
#undef STAGEB

  const int grow0 = tm * 128 + wm * 64 + (l >> 4) * 4;
  const int gcol0 = tn * 128 + wn * 64 + (l & 15);
#pragma unroll
  for (int ni = 0; ni < 4; ++ni) {
    const int col = gcol0 + ni * 16;
    const float bv = bias[col];
#pragma unroll
    for (int mi = 0; mi < 4; ++mi) {
      const int row = grow0 + mi * 16;
#pragma unroll
      for (int r = 0; r < 4; ++r) {
        float v = fmaxf(acc[mi][ni][r] + bv, 0.f);
        C[(size_t)(row + r) * N_HID + col] = f2h(v);
      }
    }
  }
}

// ---- FUSED GEMM2 + convex + gather (unchanged from R15 best) ----
__global__ __launch_bounds__(1024, 8) void gemm2_convex(
    const ushort* __restrict__ A,      // h chunk [curM][1024] f16
    const ushort* __restrict__ Bw,     // w2h [256][1024] f16
    const float* __restrict__ bias,    // b2 [256] f32
    const int* __restrict__ idxp,      // idx + m0
    float* __restrict__ out) {         // out + m0
  __shared__ ushort smem[20480];       // 40960 B
  const int tid = threadIdx.x;
  const int w = tid >> 6, l = tid & 63;
  const int wm = w >> 2, wn = w & 3;   // 4x4 wave grid
  const int m0r = blockIdx.x * 64;

  f32x4 acc[4];
#pragma unroll
  for (int i = 0; i < 4; ++i) acc[i] = {0.f, 0.f, 0.f, 0.f};

  const int srow = tid >> 2;                        // staging row
  const int scs = (tid & 3) ^ ((srow >> 1) & 3);    // inverse-swizzled src chunk
  const ushort* gA = A + (size_t)(m0r + srow) * N_HID + scs * 8;
  const ushort* gB = Bw + (size_t)srow * N_HID + scs * 8;

#define STAGE(kt, buf)                                                  \
  {                                                                     \
    if (tid < 256) async_copy16(gA + (kt) * 32, smem + (buf) * 2048 + tid * 8); \
    async_copy16(gB + (kt) * 32, smem + 4096 + (buf) * 8192 + tid * 8); \
  }

  STAGE(0, 0);
  __syncthreads();

  const int arow = wm * 16 + (l & 15);
  const int brow0 = wn * 64 + (l & 15);
  const int kx = (((l >> 4) ^ ((l >> 1) & 3)) * 8);

  for (int kt = 0; kt < 32; ++kt) {
    const int buf = kt & 1;
    if (kt < 31) STAGE(kt + 1, buf ^ 1);
    f16x8 af = *(const f16x8*)(smem + buf * 2048 + arow * 32 + kx);
#pragma unroll
    for (int ni = 0; ni < 4; ++ni) {
      f16x8 bf = *(const f16x8*)(smem + 4096 + buf * 8192 + (brow0 + ni * 16) * 32 + kx);
      acc[ni] = __builtin_amdgcn_mfma_f32_16x16x32_f16(af, bf, acc[ni], 0, 0, 0);
    }
    __syncthreads();
  }
#undef STAGE

  // epilogue: x_ tile -> f16 in LDS (aliases staging; all reads barrier-done)
  {
    const int r0 = wm * 16 + (l >> 4) * 4;
    const int c0 = wn * 64 + (l & 15);
#pragma unroll
    for (int ni = 0; ni < 4; ++ni) {
      const int col = c0 + ni * 16;
      const float bv = bias[col];
#pragma unroll
      for (int r = 0; r < 4; ++r)
        smem[(r0 + r) * 256 + col] = f2h(acc[ni][r] + bv);
    }
  }
  __syncthreads();

  // ---- convex: 16 lanes/row, 16 feats/lane in 8 NAMED u32 words ----
  const int q = l & 15;
  const int row = w * 4 + (l >> 4);        // 0..63
  u32 w0, w1, w2, w3, w4, w5, w6, w7;
  {
    const uint4* src = reinterpret_cast<const uint4*>(smem + row * 256 + q * 16);
    uint4 v0 = src[0], v1 = src[1];
    w0 = v0.x; w1 = v0.y; w2 = v0.z; w3 = v0.w;
    w4 = v1.x; w5 = v1.y; w6 = v1.z; w7 = v1.w;
  }
  const int ii = idxp[m0r + row];
  const int upIdx = ((l - 1) & 63) * 4;
  const int dnIdx = ((l + 1) & 63) * 4;
  const bool fixP = (q == 0);
  const bool fixN = (q == 15);
  const f16x2 halfc = {(_Float16)0.5f, (_Float16)0.5f};

  u32 P = __builtin_amdgcn_ds_bpermute(upIdx, w7);
  u32 N = __builtin_amdgcn_ds_bpermute(dnIdx, w0);

#define AB(hi, lo) as_h2(__builtin_amdgcn_alignbit((hi), (lo), 16))
#define UPD(wj, sa, sb) wj = as_u32(min2(as_h2(wj), ((sa) + (sb)) * halfc))
#pragma unroll 2
  for (int it = 0; it < N_IT; ++it) {
    const u32 Pf = fixP ? 0x7C000000u : P;   // prev.hi = +inf (feat -1)
    const u32 Nf = fixN ? 0x00007C00u : N;   // next.lo = +inf (feat 256)
    f16x2 s0 = AB(w0, Pf), s1 = AB(w1, w0), s2 = AB(w2, w1), s3 = AB(w3, w2);
    f16x2 s4 = AB(w4, w3), s5 = AB(w5, w4), s6 = AB(w6, w5), s7 = AB(w7, w6);
    f16x2 s8 = AB(Nf, w7);
    UPD(w7, s7, s8);
    UPD(w0, s0, s1);
    P = __builtin_amdgcn_ds_bpermute(upIdx, w7);
    N = __builtin_amdgcn_ds_bpermute(dnIdx, w0);
    UPD(w1, s1, s2); UPD(w2, s2, s3); UPD(w3, s3, s4);
    UPD(w4, s4, s5); UPD(w5, s5, s6); UPD(w6, s6, s7);
  }
#undef AB
#undef UPD

  // gather feature ii: 7-cndmask tree over 8 words, half pick, cvt, shfl
  const int sel = (ii >> 1) & 7;
  u32 a0 = (sel & 4) ? w4 : w0, a1 = (sel & 4) ? w5 : w1;
  u32 a2 = (sel & 4) ? w6 : w2, a3 = (sel & 4) ? w7 : w3;
  u32 b0 = (sel & 2) ? a2 : a0, b1 = (sel & 2) ? a3 : a1;
  u32 c0 = (sel & 1) ? b1 : b0;
  ushort hv = (ii & 1) ? (ushort)(c0 >> 16) : (ushort)(c0 & 0xffffu);
  float v = (float)__builtin_bit_cast(_Float16, hv);
  v = __shfl(v, (l & ~15) | (ii >> 4));
  if (q == 0) out[m0r + row] = v;
}

extern "C" void kernel_launch(void* const* d_in, const int* in_sizes, int n_in,
                              void* d_out, int out_size, void* d_ws, size_t ws_size,
                              hipStream_t stream) {
  const float* x = (const float*)d_in[0];
  const float* W1 = (const float*)d_in[1];
  const float* b1 = (const float*)d_in[2];
  const float* W2 = (const float*)d_in[3];
  const float* b2 = (const float*)d_in[4];
  float* out = (float*)d_out;

  // workspace layout (16B-aligned)
  char* ws = (char*)d_ws;
  ushort* w1h = (ushort*)ws;                    //    524,288 B
  ushort* w2h = (ushort*)(ws + 524288);         //    524,288 B
  int*    idx = (int*)  (ws + 1048576);         //    131,072 B
  ushort* h   = (ushort*)(ws + 1179648);        // chunk*2048 B  h f16 [chunk,1024]

  const size_t fixed = 1179648;
  int chunk = 2048;
  if (ws_size >= fixed + (size_t)32768 * 2048) chunk = 32768;
  else if (ws_size >= fixed + (size_t)16384 * 2048) chunk = 16384;
  else if (ws_size >= fixed + (size_t)8192 * 2048) chunk = 8192;
  else if (ws_size >= fixed + (size_t)4096 * 2048) chunk = 4096;

  prep_kernel<<<384, 256, 0, stream>>>(x, W1, W2, w1h, w2h, idx);

  for (int m0 = 0; m0 < B_ROWS; m0 += chunk) {
    int curM = (B_ROWS - m0 < chunk) ? (B_ROWS - m0) : chunk;
    dim3 g1((curM / 128) * (N_HID / 128));
    gemm1_x<<<g1, 256, 0, stream>>>(x + (size_t)m0 * 257, w1h, b1, h,
                                    N_HID / 128);
    gemm2_convex<<<curM / 64, 1024, 0, stream>>>(h, w2h, b2, idx + m0, out + m0);
  }
}

// Round 17
// 122.089 us; speedup vs baseline: 1.2039x; 1.0037x over previous
//
#include <hip/hip_runtime.h>
#include <stdint.h>

#define B_ROWS 32768
#define N_INP 256
#define N_HID 1024
#define NF 256
#define N_IT 100

typedef __attribute__((ext_vector_type(8))) _Float16 f16x8;
typedef __attribute__((ext_vector_type(4))) float f32x4;
typedef __attribute__((ext_vector_type(2))) _Float16 f16x2;
typedef float f32x4a __attribute__((ext_vector_type(4), aligned(4)));  // 4B-aligned vec load
typedef uint32_t u32;

__device__ __forceinline__ ushort f2h(float f) {
  _Float16 h = (_Float16)f;               // v_cvt_f16_f32, RNE
  return *reinterpret_cast<ushort*>(&h);
}

// pack two f32 -> two f16 (RNE) in one u32
__device__ __forceinline__ u32 pkh(float a, float b) {
  _Float16 ha = (_Float16)a, hb = (_Float16)b;
  return (u32)*reinterpret_cast<ushort*>(&ha) |
         ((u32)*reinterpret_cast<ushort*>(&hb) << 16);
}

__device__ __forceinline__ void async_copy16(const void* g, void* l) {
  __builtin_amdgcn_global_load_lds(
      (const __attribute__((address_space(1))) void*)g,
      (__attribute__((address_space(3))) void*)l, 16, 0, 0);
}

__device__ __forceinline__ f16x2 as_h2(u32 x) { return __builtin_bit_cast(f16x2, x); }
__device__ __forceinline__ u32 as_u32(f16x2 x) { return __builtin_bit_cast(u32, x); }
__device__ __forceinline__ f16x2 min2(f16x2 a, f16x2 b) {
  f16x2 r;
  asm("v_pk_min_f16 %0, %1, %2" : "=v"(r) : "v"(a), "v"(b));
  return r;
}

// ---- prepass (small): convert W1/W2 -> f16; extract idx ----
__global__ void prep_kernel(const float* __restrict__ x,
                            const float* __restrict__ W1,
                            const float* __restrict__ W2,
                            ushort* __restrict__ w1h,
                            ushort* __restrict__ w2h,
                            int* __restrict__ idx) {
  if (blockIdx.x < 256) {
    int t = blockIdx.x * 256 + threadIdx.x;          // 65536 threads
    float4 a = reinterpret_cast<const float4*>(W1)[t];
    float4 b = reinterpret_cast<const float4*>(W2)[t];
    reinterpret_cast<ushort4*>(w1h)[t] = make_ushort4(f2h(a.x), f2h(a.y), f2h(a.z), f2h(a.w));
    reinterpret_cast<ushort4*>(w2h)[t] = make_ushort4(f2h(b.x), f2h(b.y), f2h(b.z), f2h(b.w));
  } else {
    int r = (blockIdx.x - 256) * 256 + threadIdx.x;  // 32768 rows
    idx[r] = (int)rintf(x[(size_t)r * 257 + 256] * 255.0f);
  }
}

// ---- GEMM1 with fused x->f16 conversion (unchanged from R16) ----
__global__ __launch_bounds__(256) void gemm1_x(
    const float* __restrict__ X,       // [M,257] f32 (chunk base)
    const ushort* __restrict__ Bw,     // w1h [1024][256] f16
    const float* __restrict__ bias,    // b1
    ushort* __restrict__ C,            // h [M,1024] f16
    int ntN) {
  __shared__ ushort As[2][128 * 64];
  __shared__ ushort Bs[2][128 * 64];
  const int t = threadIdx.x;
  const int w = t >> 6, l = t & 63;
  int bid = blockIdx.x;
  if (((int)gridDim.x & 7) == 0) {
    int cpx = (int)gridDim.x >> 3;
    bid = (bid & 7) * cpx + (bid >> 3);
  }
  const int tm = bid / ntN, tn = bid % ntN;
  const int wm = w >> 1, wn = w & 1;

  const float* Xb = X + (size_t)(tm * 128) * 257;
  const char* Bb = (const char*)(Bw + (size_t)tn * 128 * 256);
  const int sB = 512;
  const int lrow = l >> 3;
  const int lcol = (l & 7) * 16;

  const int ar0 = t >> 3;
  const int ak0 = (t & 7) * 8;

  f32x4a a0, a1, a2, a3, a4, a5, a6, a7;
#define LOADA(kt)                                                        \
  {                                                                      \
    const float* p0 = Xb + (size_t)ar0 * 257 + (kt) * 64 + ak0;          \
    const float* p1 = p0 + (size_t)32 * 257;                             \
    const float* p2 = p0 + (size_t)64 * 257;                             \
    const float* p3 = p0 + (size_t)96 * 257;                             \
    a0 = *(const f32x4a*)p0; a1 = *(const f32x4a*)(p0 + 4);              \
    a2 = *(const f32x4a*)p1; a3 = *(const f32x4a*)(p1 + 4);              \
    a4 = *(const f32x4a*)p2; a5 = *(const f32x4a*)(p2 + 4);              \
    a6 = *(const f32x4a*)p3; a7 = *(const f32x4a*)(p3 + 4);              \
  }
#define WRITEA(buf)                                                      \
  {                                                                      \
    uint4* d = (uint4*)((char*)&As[buf][0] + t * 16);                    \
    d[0]   = make_uint4(pkh(a0.x, a0.y), pkh(a0.z, a0.w),                \
                        pkh(a1.x, a1.y), pkh(a1.z, a1.w));               \
    d[256] = make_uint4(pkh(a2.x, a2.y), pkh(a2.z, a2.w),                \
                        pkh(a3.x, a3.y), pkh(a3.z, a3.w));               \
    d[512] = make_uint4(pkh(a4.x, a4.y), pkh(a4.z, a4.w),                \
                        pkh(a5.x, a5.y), pkh(a5.z, a5.w));               \
    d[768] = make_uint4(pkh(a6.x, a6.y), pkh(a6.z, a6.w),                \
                        pkh(a7.x, a7.y), pkh(a7.z, a7.w));               \
  }
#define STAGEB(kt, buf)                                                  \
  {                                                                      \
    const char* gb = Bb + lrow * sB + (kt) * 128 + lcol;                 \
    _Pragma("unroll") for (int i = 0; i < 4; ++i) {                      \
      int c = w * 4 + i;                                                 \
      async_copy16(gb + c * 8 * sB, (char*)&Bs[buf][0] + c * 1024);      \
    }                                                                    \
  }

  f32x4 acc[4][4];
#pragma unroll
  for (int i = 0; i < 4; ++i)
#pragma unroll
    for (int j = 0; j < 4; ++j) acc[i][j] = {0.f, 0.f, 0.f, 0.f};

  LOADA(0);
  STAGEB(0, 0);
  WRITEA(0);
  __syncthreads();

  const int arow = wm * 64 + (l & 15);
  const int brow = wn * 64 + (l & 15);
  const int koff = (l >> 4) * 8;

  for (int kt = 0; kt < 4; ++kt) {
    const int buf = kt & 1;
    if (kt < 3) {
      LOADA(kt + 1);
      STAGEB(kt + 1, buf ^ 1);
    }
#pragma unroll
    for (int ks = 0; ks < 2; ++ks) {
      f16x8 af[4], bfr[4];
#pragma unroll
      for (int mi = 0; mi < 4; ++mi)
        af[mi] = *(const f16x8*)&As[buf][(arow + mi * 16) * 64 + ks * 32 + koff];
#pragma unroll
      for (int ni = 0; ni < 4; ++ni)
        bfr[ni] = *(const f16x8*)&Bs[buf][(brow + ni * 16) * 64 + ks * 32 + koff];
#pragma unroll
      for (int mi = 0; mi < 4; ++mi)
#pragma unroll
        for (int ni = 0; ni < 4; ++ni)
          acc[mi][ni] = __builtin_amdgcn_mfma_f32_16x16x32_f16(
              af[mi], bfr[ni], acc[mi][ni], 0, 0, 0);
    }
    if (kt < 3) WRITEA(buf ^ 1);
    __syncthreads();
  }
#undef LOADA
#undef WRITEA
#undef STAGEB

  const int grow0 = tm * 128 + wm * 64 + (l >> 4) * 4;
  const int gcol0 = tn * 128 + wn * 64 + (l & 15);
#pragma unroll
  for (int ni = 0; ni < 4; ++ni) {
    const int col = gcol0 + ni * 16;
    const float bv = bias[col];
#pragma unroll
    for (int mi = 0; mi < 4; ++mi) {
      const int row = grow0 + mi * 16;
#pragma unroll
      for (int r = 0; r < 4; ++r) {
        float v = fmaxf(acc[mi][ni][r] + bv, 0.f);
        C[(size_t)(row + r) * N_HID + col] = f2h(v);
      }
    }
  }
}

// ---- FUSED GEMM2 + convex + gather, now with T3/T4-lite K-loop ----
// 3 staging buffers (A 3x4KB @0, B 3x16KB @12KB = 60KB LDS); loads for step
// kt issued at iter kt-2; counted vmcnt per wave role (waves 0-3 stage A+B ->
// vmcnt(2); waves 4-15 B only -> vmcnt(1)); ONE raw s_barrier per step placed
// AFTER the vmcnt (publishes stage(kt) AND closes prior readers of the buffer
// stage(kt+2) overwrites). vmcnt(0) only at the tail. x_ f16 tile [64][256]
// (32KB) aliases staging after a full __syncthreads drain.
__global__ __launch_bounds__(1024, 8) void gemm2_convex(
    const ushort* __restrict__ A,      // h chunk [curM][1024] f16
    const ushort* __restrict__ Bw,     // w2h [256][1024] f16
    const float* __restrict__ bias,    // b2 [256] f32
    const int* __restrict__ idxp,      // idx + m0
    float* __restrict__ out) {         // out + m0
  __shared__ ushort smem[30720];       // 61440 B
  const int tid = threadIdx.x;
  const int w = tid >> 6, l = tid & 63;
  const int wm = w >> 2, wn = w & 3;   // 4x4 wave grid
  const int m0r = blockIdx.x * 64;

  f32x4 acc[4];
#pragma unroll
  for (int i = 0; i < 4; ++i) acc[i] = {0.f, 0.f, 0.f, 0.f};

  const int srow = tid >> 2;                        // staging row
  const int scs = (tid & 3) ^ ((srow >> 1) & 3);    // inverse-swizzled src chunk
  const ushort* gA = A + (size_t)(m0r + srow) * N_HID + scs * 8;
  const ushort* gB = Bw + (size_t)srow * N_HID + scs * 8;

#define STAGE(kt, buf)                                                       \
  {                                                                          \
    if (tid < 256) async_copy16(gA + (kt) * 32, smem + (buf) * 2048 + tid * 8); \
    async_copy16(gB + (kt) * 32, smem + 6144 + (buf) * 8192 + tid * 8);      \
  }

  STAGE(0, 0);
  STAGE(1, 1);

  const int arow = wm * 16 + (l & 15);
  const int brow0 = wn * 64 + (l & 15);
  const int kx = (((l >> 4) ^ ((l >> 1) & 3)) * 8);

  int bufr = 0;   // kt % 3
  int bufs = 2;   // (kt+2) % 3
  for (int kt = 0; kt < 31; ++kt) {
    if (w < 4) asm volatile("s_waitcnt vmcnt(2)" ::: "memory");
    else       asm volatile("s_waitcnt vmcnt(1)" ::: "memory");
    __builtin_amdgcn_s_barrier();
    asm volatile("" ::: "memory");
    if (kt < 30) STAGE(kt + 2, bufs);
    f16x8 af = *(const f16x8*)(smem + bufr * 2048 + arow * 32 + kx);
#pragma unroll
    for (int ni = 0; ni < 4; ++ni) {
      f16x8 bf = *(const f16x8*)(smem + 6144 + bufr * 8192 + (brow0 + ni * 16) * 32 + kx);
      acc[ni] = __builtin_amdgcn_mfma_f32_16x16x32_f16(af, bf, acc[ni], 0, 0, 0);
    }
    bufr = (bufr == 2) ? 0 : bufr + 1;
    bufs = (bufs == 2) ? 0 : bufs + 1;
  }
  // tail step kt=31 (buffer bufr == 1): all staging must have landed
  asm volatile("s_waitcnt vmcnt(0)" ::: "memory");
  __builtin_amdgcn_s_barrier();
  asm volatile("" ::: "memory");
  {
    f16x8 af = *(const f16x8*)(smem + bufr * 2048 + arow * 32 + kx);
#pragma unroll
    for (int ni = 0; ni < 4; ++ni) {
      f16x8 bf = *(const f16x8*)(smem + 6144 + bufr * 8192 + (brow0 + ni * 16) * 32 + kx);
      acc[ni] = __builtin_amdgcn_mfma_f32_16x16x32_f16(af, bf, acc[ni], 0, 0, 0);
    }
  }
#undef STAGE
  __syncthreads();   // close all reads before aliasing writes

  // epilogue: x_ tile -> f16 in LDS (aliases staging)
  {
    const int r0 = wm * 16 + (l >> 4) * 4;
    const int c0 = wn * 64 + (l & 15);
#pragma unroll
    for (int ni = 0; ni < 4; ++ni) {
      const int col = c0 + ni * 16;
      const float bv = bias[col];
#pragma unroll
      for (int r = 0; r < 4; ++r)
        smem[(r0 + r) * 256 + col] = f2h(acc[ni][r] + bv);
    }
  }
  __syncthreads();

  // ---- convex: 16 lanes/row, 16 feats/lane in 8 NAMED u32 words ----
  const int q = l & 15;
  const int row = w * 4 + (l >> 4);        // 0..63
  u32 w0, w1, w2, w3, w4, w5, w6, w7;
  {
    const uint4* src = reinterpret_cast<const uint4*>(smem + row * 256 + q * 16);
    uint4 v0 = src[0], v1 = src[1];
    w0 = v0.x; w1 = v0.y; w2 = v0.z; w3 = v0.w;
    w4 = v1.x; w5 = v1.y; w6 = v1.z; w7 = v1.w;
  }
  const int ii = idxp[m0r + row];
  const int upIdx = ((l - 1) & 63) * 4;
  const int dnIdx = ((l + 1) & 63) * 4;
  const bool fixP = (q == 0);
  const bool fixN = (q == 15);
  const f16x2 halfc = {(_Float16)0.5f, (_Float16)0.5f};

  u32 P = __builtin_amdgcn_ds_bpermute(upIdx, w7);
  u32 N = __builtin_amdgcn_ds_bpermute(dnIdx, w0);

#define AB(hi, lo) as_h2(__builtin_amdgcn_alignbit((hi), (lo), 16))
#define UPD(wj, sa, sb) wj = as_u32(min2(as_h2(wj), ((sa) + (sb)) * halfc))
#pragma unroll 2
  for (int it = 0; it < N_IT; ++it) {
    const u32 Pf = fixP ? 0x7C000000u : P;   // prev.hi = +inf (feat -1)
    const u32 Nf = fixN ? 0x00007C00u : N;   // next.lo = +inf (feat 256)
    f16x2 s0 = AB(w0, Pf), s1 = AB(w1, w0), s2 = AB(w2, w1), s3 = AB(w3, w2);
    f16x2 s4 = AB(w4, w3), s5 = AB(w5, w4), s6 = AB(w6, w5), s7 = AB(w7, w6);
    f16x2 s8 = AB(Nf, w7);
    UPD(w7, s7, s8);
    UPD(w0, s0, s1);
    P = __builtin_amdgcn_ds_bpermute(upIdx, w7);
    N = __builtin_amdgcn_ds_bpermute(dnIdx, w0);
    UPD(w1, s1, s2); UPD(w2, s2, s3); UPD(w3, s3, s4);
    UPD(w4, s4, s5); UPD(w5, s5, s6); UPD(w6, s6, s7);
  }
#undef AB
#undef UPD

  // gather feature ii: 7-cndmask tree over 8 words, half pick, cvt, shfl
  const int sel = (ii >> 1) & 7;
  u32 a0 = (sel & 4) ? w4 : w0, a1 = (sel & 4) ? w5 : w1;
  u32 a2 = (sel & 4) ? w6 : w2, a3 = (sel & 4) ? w7 : w3;
  u32 b0 = (sel & 2) ? a2 : a0, b1 = (sel & 2) ? a3 : a1;
  u32 c0 = (sel & 1) ? b1 : b0;
  ushort hv = (ii & 1) ? (ushort)(c0 >> 16) : (ushort)(c0 & 0xffffu);
  float v = (float)__builtin_bit_cast(_Float16, hv);
  v = __shfl(v, (l & ~15) | (ii >> 4));
  if (q == 0) out[m0r + row] = v;
}

extern "C" void kernel_launch(void* const* d_in, const int* in_sizes, int n_in,
                              void* d_out, int out_size, void* d_ws, size_t ws_size,
                              hipStream_t stream) {
  const float* x = (const float*)d_in[0];
  const float* W1 = (const float*)d_in[1];
  const float* b1 = (const float*)d_in[2];
  const float* W2 = (const float*)d_in[3];
  const float* b2 = (const float*)d_in[4];
  float* out = (float*)d_out;

  // workspace layout (16B-aligned)
  char* ws = (char*)d_ws;
  ushort* w1h = (ushort*)ws;                    //    524,288 B
  ushort* w2h = (ushort*)(ws + 524288);         //    524,288 B
  int*    idx = (int*)  (ws + 1048576);         //    131,072 B
  ushort* h   = (ushort*)(ws + 1179648);        // chunk*2048 B  h f16 [chunk,1024]

  const size_t fixed = 1179648;
  int chunk = 2048;
  if (ws_size >= fixed + (size_t)32768 * 2048) chunk = 32768;
  else if (ws_size >= fixed + (size_t)16384 * 2048) chunk = 16384;
  else if (ws_size >= fixed + (size_t)8192 * 2048) chunk = 8192;
  else if (ws_size >= fixed + (size_t)4096 * 2048) chunk = 4096;

  prep_kernel<<<384, 256, 0, stream>>>(x, W1, W2, w1h, w2h, idx);

  for (int m0 = 0; m0 < B_ROWS; m0 += chunk) {
    int curM = (B_ROWS - m0 < chunk) ? (B_ROWS - m0) : chunk;
    dim3 g1((curM / 128) * (N_HID / 128));
    gemm1_x<<<g1, 256, 0, stream>>>(x + (size_t)m0 * 257, w1h, b1, h,
                                    N_HID / 128);
    gemm2_convex<<<curM / 64, 1024, 0, stream>>>(h, w2h, b2, idx + m0, out + m0);
  }
}